// Round 3
// baseline (1214.298 us; speedup 1.0000x reference)
//
#include <hip/hip_runtime.h>
#include <hip/hip_bf16.h>

typedef __attribute__((ext_vector_type(8))) short bf16x8_t;   // MFMA A/B frag (8 bf16)
typedef __attribute__((ext_vector_type(4))) float f32x4_t;    // MFMA C/D frag
typedef __attribute__((ext_vector_type(4))) float fv4;
typedef __attribute__((ext_vector_type(4))) unsigned short us4_t;
typedef __attribute__((ext_vector_type(8))) unsigned short us8_t;

// Problem constants
static constexpr int BB = 16, NN = 4096, DD = 768, HH = 16, EE = 48;

__device__ __forceinline__ unsigned short f2bf(float f) {
  unsigned int u = __float_as_uint(f);
  u += 0x7fffu + ((u >> 16) & 1u);   // RNE; inputs are finite
  return (unsigned short)(u >> 16);
}

__device__ __forceinline__ void load_lds16(const void* g, void* l) {
  __builtin_amdgcn_global_load_lds((const __attribute__((address_space(1))) void*)g,
                                   (__attribute__((address_space(3))) void*)l, 16, 0, 0);
}

// ---------------------------------------------------------------------------
// K1: cast x -> bf16, {wq,wk,wv} -> wcat bf16 [2304][768], {bq,bk,bv} -> bcat f32
// ---------------------------------------------------------------------------
__global__ __launch_bounds__(256) void cast_all(
    const float* __restrict__ x,
    const float* __restrict__ wq, const float* __restrict__ wk, const float* __restrict__ wv,
    const float* __restrict__ bq, const float* __restrict__ bk, const float* __restrict__ bv,
    unsigned short* __restrict__ xb, unsigned short* __restrict__ wcat, float* __restrict__ bcat)
{
  const long NX4 = (long)BB * NN * DD / 4;       // 12582912 float4 slots
  const long NW4 = 3L * DD * DD / 4;             // 442368
  const long NBS = 3L * DD;                      // 2304
  long stride = (long)gridDim.x * blockDim.x;
  for (long i = (long)blockIdx.x * blockDim.x + threadIdx.x; i < NX4 + NW4 + NBS; i += stride) {
    if (i < NX4) {
      fv4 v = ((const fv4*)x)[i];
      us4_t o; o.x = f2bf(v.x); o.y = f2bf(v.y); o.z = f2bf(v.z); o.w = f2bf(v.w);
      ((us4_t*)xb)[i] = o;
    } else if (i < NX4 + NW4) {
      long w = i - NX4;
      long row = (w * 4) / DD;
      long col = (w * 4) % DD;
      const float* src = (row < DD)     ? (wq + row * DD + col)
                       : (row < 2 * DD) ? (wk + (row - DD) * DD + col)
                                        : (wv + (row - 2 * DD) * DD + col);
      fv4 v = *(const fv4*)src;
      us4_t o; o.x = f2bf(v.x); o.y = f2bf(v.y); o.z = f2bf(v.z); o.w = f2bf(v.w);
      ((us4_t*)wcat)[w] = o;
    } else {
      long j = i - NX4 - NW4;
      bcat[j] = (j < DD) ? bq[j] : (j < 2 * DD) ? bk[j - DD] : bv[j - 2 * DD];
    }
  }
}

// ---------------------------------------------------------------------------
// K2/K5: bf16 GEMM, C[m][n] = sum_k A[m][k] * Bt[n][k] + bias[n]
// 128x128 tile, BK=32, 4 waves (2x2 of 64x64), m97 structure.
// OUT_BF16=1 -> bf16 store, else f32 store.
// ---------------------------------------------------------------------------
template<int OUT_BF16>
__global__ __launch_bounds__(256) void gemm_bt(
    const unsigned short* __restrict__ A, int lda, long aStride,
    const unsigned short* __restrict__ Bt, int ldb, long bStride,
    void* __restrict__ Cv, int ldc, long cStride,
    const float* __restrict__ bias, int K)
{
  __shared__ unsigned short As[128 * 32];
  __shared__ unsigned short Bs[128 * 32];
  const int zb = blockIdx.z;
  const unsigned short* Ab = A + (long)zb * aStride;
  const unsigned short* Bb = Bt + (long)zb * bStride;
  const long m0 = (long)blockIdx.x * 128;
  const int n0 = blockIdx.y * 128;
  const int t = threadIdx.x;
  const int wave = t >> 6, lane = t & 63;
  const int wr = wave >> 1, wc = wave & 1;

  f32x4_t acc[4][4] = {};

  // staging geometry: byte offset o in 8KB tile; row = o>>6 (32 bf16 = 64B rows)
  const int o0 = t * 16;
  const int row0 = o0 >> 6, kc0 = (o0 & 63) >> 1;
  const int o1 = 4096 + t * 16;
  const int row1 = o1 >> 6, kc1 = (o1 & 63) >> 1;
  unsigned short* ldsA = As + wave * 512;  // + lane*16B by HW
  unsigned short* ldsB = Bs + wave * 512;

  for (int kt = 0; kt < K; kt += 32) {
    load_lds16(Ab + (m0 + row0) * (long)lda + kt + kc0, ldsA);
    load_lds16(Ab + (m0 + row1) * (long)lda + kt + kc1, ldsA + 2048);
    load_lds16(Bb + (long)(n0 + row0) * ldb + kt + kc0, ldsB);
    load_lds16(Bb + (long)(n0 + row1) * ldb + kt + kc1, ldsB + 2048);
    __syncthreads();
    bf16x8_t af[4], bfr[4];
    const int kofs = (lane >> 4) << 3;
#pragma unroll
    for (int f = 0; f < 4; ++f) {
      af[f]  = *(const bf16x8_t*)&As[(wr * 64 + f * 16 + (lane & 15)) * 32 + kofs];
      bfr[f] = *(const bf16x8_t*)&Bs[(wc * 64 + f * 16 + (lane & 15)) * 32 + kofs];
    }
#pragma unroll
    for (int i = 0; i < 4; ++i)
#pragma unroll
      for (int j = 0; j < 4; ++j)
        acc[i][j] = __builtin_amdgcn_mfma_f32_16x16x32_bf16(af[i], bfr[j], acc[i][j], 0, 0, 0);
    __syncthreads();
  }

  // epilogue: D col = lane&15, row = (lane>>4)*4 + r  (m89-verified layout)
  const int col_l = lane & 15;
  const int rbase = (lane >> 4) << 2;
#pragma unroll
  for (int i = 0; i < 4; ++i) {
#pragma unroll
    for (int r = 0; r < 4; ++r) {
      const long grow = m0 + wr * 64 + i * 16 + rbase + r;
      if (OUT_BF16) {
        unsigned short* crow = (unsigned short*)Cv + (long)zb * cStride + grow * ldc + n0 + wc * 64;
#pragma unroll
        for (int j = 0; j < 4; ++j) {
          int col = j * 16 + col_l;
          crow[col] = f2bf(acc[i][j][r] + bias[n0 + wc * 64 + col]);
        }
      } else {
        float* crow = (float*)Cv + (long)zb * cStride + grow * ldc + n0 + wc * 64;
#pragma unroll
        for (int j = 0; j < 4; ++j) {
          int col = j * 16 + col_l;
          crow[col] = acc[i][j][r] + bias[n0 + wc * 64 + col];
        }
      }
    }
  }
}

// ---------------------------------------------------------------------------
// K3a: per (b,h,nc): partial G = Q_h^T K_h over rows [nc*512, nc*512+512)
// via MFMA (plus free diag(Q^TQ), diag(K^TK) partial sums for the L2 norms).
// Writes fp32 partials to Gp[(b*H+h)*8+nc][2464]:
//   [0..2352) = G (48 rows x stride 49), [2352..2400) = nq2, [2400..2448) = nk2.
// Round-2 lesson: single block per (b,h) = 256 blocks = 11% occupancy,
// 363 GB/s, 556 us. 8-way N-split -> 2048 blocks restores TLP.
// ---------------------------------------------------------------------------
#define NCH 128
#define QSTR 136   // padded LDS stride (bf16 elems); 272B rows, 16B aligned
#define GP_STRIDE 2464

__global__ __launch_bounds__(256) void energy_partial(
    const unsigned short* __restrict__ qkv, float* __restrict__ Gp)
{
  __shared__ unsigned short Qt[48 * QSTR];
  __shared__ unsigned short Kt[48 * QSTR];
  __shared__ float G_sh[2448];   // [0..2352) G(49-stride), nq2, nk2

  const int nc = blockIdx.x, h = blockIdx.y, b = blockIdx.z;
  const int t = threadIdx.x;
  const int wave = t >> 6, lane = t & 63;

  for (int i = t; i < 2448; i += 256) G_sh[i] = 0.f;

  f32x4_t accG[3][3] = {};
  f32x4_t accQ[3] = {};
  f32x4_t accK[3] = {};

  const long baseQ = (long)b * NN * 2304 + h * 48;
  const long baseK = baseQ + 768;

  // per-i staging descriptors (slot = i*256 + t)
  int s_rr[6]; long s_base[6]; int s_cg[6]; unsigned short* s_dst[6];
  for (int i = 0; i < 6; ++i) {
    int slot = i * 256 + t;
    int mat = slot / 768;
    int rr = (slot % 768) / 6;
    int cg = slot % 6;
    s_rr[i] = rr; s_cg[i] = cg;
    s_base[i] = (mat ? baseK : baseQ) + (long)cg * 8;
    s_dst[i] = mat ? Kt : Qt;
  }
  const int jstart = t & 7;
  __syncthreads();

  const int c0 = nc * 512;
  for (int c = c0; c < c0 + 512; c += NCH) {
    us8_t v[6];
#pragma unroll
    for (int i = 0; i < 6; ++i)
      v[i] = *(const us8_t*)(qkv + s_base[i] + (long)(c + s_rr[i]) * 2304);
#pragma unroll
    for (int i = 0; i < 6; ++i) {
      unsigned short* dst = s_dst[i];
      const int cg8 = s_cg[i] * 8, rr = s_rr[i];
#pragma unroll
      for (int jj = 0; jj < 8; ++jj) {
        int j = (jstart + jj) & 7;
        dst[(cg8 + j) * QSTR + rr] = ((const unsigned short*)&v[i])[j];
      }
    }
    __syncthreads();
    // each wave reduces its own 32-row (n) slice
    const int koff = wave * 32 + ((lane >> 4) << 3);
    bf16x8_t aq[3], ak[3];
#pragma unroll
    for (int f = 0; f < 3; ++f) {
      aq[f] = *(const bf16x8_t*)&Qt[(f * 16 + (lane & 15)) * QSTR + koff];
      ak[f] = *(const bf16x8_t*)&Kt[(f * 16 + (lane & 15)) * QSTR + koff];
    }
#pragma unroll
    for (int i = 0; i < 3; ++i) {
      accQ[i] = __builtin_amdgcn_mfma_f32_16x16x32_bf16(aq[i], aq[i], accQ[i], 0, 0, 0);
      accK[i] = __builtin_amdgcn_mfma_f32_16x16x32_bf16(ak[i], ak[i], accK[i], 0, 0, 0);
#pragma unroll
      for (int j = 0; j < 3; ++j)
        accG[i][j] = __builtin_amdgcn_mfma_f32_16x16x32_bf16(aq[i], ak[j], accG[i][j], 0, 0, 0);
    }
    __syncthreads();
  }

  // cross-wave reduce G into LDS
#pragma unroll
  for (int i = 0; i < 3; ++i)
#pragma unroll
    for (int j = 0; j < 3; ++j) {
      int e = i * 16 + ((lane >> 4) << 2);
      int qi = j * 16 + (lane & 15);
#pragma unroll
      for (int r = 0; r < 4; ++r) atomicAdd(&G_sh[(e + r) * 49 + qi], accG[i][j][r]);
    }
  // diagonal lanes contribute the sum-of-squares
  if ((lane >> 4) == ((lane & 15) >> 2)) {
    int r = (lane & 15) & 3;
#pragma unroll
    for (int f = 0; f < 3; ++f) {
      atomicAdd(&G_sh[2352 + f * 16 + (lane & 15)], accQ[f][r]);
      atomicAdd(&G_sh[2400 + f * 16 + (lane & 15)], accK[f][r]);
    }
  }
  __syncthreads();

  float* out = Gp + (long)(((b * HH + h) << 3) + nc) * GP_STRIDE;
  for (int i = t; i < 2448; i += 256) out[i] = G_sh[i];
}

// ---------------------------------------------------------------------------
// K3b: per (b,h): reduce the 8 partials, norms, softmax, /tau. Writes A as
// bf16 padded [48][64] (cols 48..63 zero) for the MFMA consumer in K4.
// ---------------------------------------------------------------------------
__global__ __launch_bounds__(256) void energy_finish(
    const float* __restrict__ Gp, const float* __restrict__ tau_p,
    unsigned short* __restrict__ A_out)
{
  __shared__ float G_sh[2448];
  const int h = blockIdx.x, b = blockIdx.y;
  const int t = threadIdx.x;

  const float* base = Gp + (long)((b * HH + h) << 3) * GP_STRIDE;
  for (int i = t; i < 2448; i += 256) {
    float s = 0.f;
#pragma unroll
    for (int nc = 0; nc < 8; ++nc) s += base[(long)nc * GP_STRIDE + i];
    G_sh[i] = s;
  }
  __syncthreads();

  if (t < 48) {
    const float tau = *tau_p;
    const float nq = fmaxf(sqrtf(G_sh[2352 + t]), 1e-12f);
    float row[48];
    float mx = -1e30f;
#pragma unroll 1
    for (int qi = 0; qi < 48; ++qi) {
      float nk = fmaxf(sqrtf(G_sh[2400 + qi]), 1e-12f);
      float g = G_sh[t * 49 + qi] / (nq * nk);
      row[qi] = g; mx = fmaxf(mx, g);
    }
    float s = 0.f;
#pragma unroll 1
    for (int qi = 0; qi < 48; ++qi) { row[qi] = __expf(row[qi] - mx); s += row[qi]; }
    const float inv = 1.f / (s * tau);
    unsigned short* dst = A_out + (((long)b * HH + h) * 48) * 64 + (long)t * 64;
#pragma unroll 1
    for (int qi = 0; qi < 48; ++qi) dst[qi] = f2bf(row[qi] * inv);
#pragma unroll 1
    for (int qi = 48; qi < 64; ++qi) dst[qi] = 0;
  }
}

// ---------------------------------------------------------------------------
// K4: Btf[b][no][h*48+e] = sum_qi A_h[e][qi] * wo[no][h*48+qi]   (MFMA, K=48
// padded to 64). A-operand = wo rows (qi-contiguous), B-operand = A_h rows.
// ---------------------------------------------------------------------------
__global__ __launch_bounds__(256) void build_btf(
    const unsigned short* __restrict__ A_ws, const float* __restrict__ wo,
    unsigned short* __restrict__ btf)
{
  __shared__ unsigned short Wsh[128 * 72];
  __shared__ unsigned short Ash[48 * 72];
  const int nchunk = blockIdx.x, h = blockIdx.y, b = blockIdx.z;
  const int t = threadIdx.x;
  const int wave = t >> 6, lane = t & 63;
  const int no0 = nchunk * 128;

  for (int i = t; i < 128 * 64; i += 256) {
    int r = i >> 6, c = i & 63;
    Wsh[r * 72 + c] = (c < 48) ? f2bf(wo[(long)(no0 + r) * DD + h * 48 + c]) : (unsigned short)0;
  }
  const unsigned short* Asrc = A_ws + ((long)b * HH + h) * 48 * 64;
  for (int i = t; i < 48 * 64; i += 256) {
    int r = i >> 6, c = i & 63;
    Ash[r * 72 + c] = Asrc[r * 64 + c];   // already zero-padded in cols 48..63
  }
  __syncthreads();

  f32x4_t acc[2][3] = {};
#pragma unroll
  for (int ks = 0; ks < 2; ++ks) {
    const int k0 = ks * 32 + ((lane >> 4) << 3);
    bf16x8_t af[2], bfr[3];
#pragma unroll
    for (int mi = 0; mi < 2; ++mi)
      af[mi] = *(const bf16x8_t*)&Wsh[(wave * 32 + mi * 16 + (lane & 15)) * 72 + k0];
#pragma unroll
    for (int nj = 0; nj < 3; ++nj)
      bfr[nj] = *(const bf16x8_t*)&Ash[(nj * 16 + (lane & 15)) * 72 + k0];
#pragma unroll
    for (int mi = 0; mi < 2; ++mi)
#pragma unroll
      for (int nj = 0; nj < 3; ++nj)
        acc[mi][nj] = __builtin_amdgcn_mfma_f32_16x16x32_bf16(af[mi], bfr[nj], acc[mi][nj], 0, 0, 0);
  }

  const int col_l = lane & 15;
  const int rbase = (lane >> 4) << 2;
#pragma unroll
  for (int mi = 0; mi < 2; ++mi)
#pragma unroll
    for (int r = 0; r < 4; ++r) {
      int no = no0 + wave * 32 + mi * 16 + rbase + r;
      unsigned short* dst = btf + ((long)b * DD + no) * DD + h * 48;
#pragma unroll
      for (int nj = 0; nj < 3; ++nj)
        dst[nj * 16 + col_l] = f2bf(acc[mi][nj][r]);
    }
}

// ---------------------------------------------------------------------------
extern "C" void kernel_launch(void* const* d_in, const int* in_sizes, int n_in,
                              void* d_out, int out_size, void* d_ws, size_t ws_size,
                              hipStream_t stream)
{
  (void)in_sizes; (void)n_in; (void)out_size;
  const float* x   = (const float*)d_in[0];
  const float* wq  = (const float*)d_in[1];
  const float* bq  = (const float*)d_in[2];
  const float* wk  = (const float*)d_in[3];
  const float* bk  = (const float*)d_in[4];
  const float* wv  = (const float*)d_in[5];
  const float* bv  = (const float*)d_in[6];
  const float* wo  = (const float*)d_in[7];
  const float* bo  = (const float*)d_in[8];
  const float* tau = (const float*)d_in[9];

  char* ws = (char*)d_ws;
  // layout (bytes)
  unsigned short* xb   = (unsigned short*)(ws + 0);           // 100663296 (dead after K2)
  unsigned short* qkv  = (unsigned short*)(ws + 100663296L);  // 301989888
  unsigned short* wcat = (unsigned short*)(ws + 402653184L);  // 3538944
  float*          bcat = (float*)         (ws + 406192128L);  // 9216
  // Aliases into the dead xb region (xb only read by K2; K3a/K3b/K4 are
  // stream-ordered after it):
  //   A_ws at ws+0        : B*H*48*64*2      = 1572864 B
  //   Gp   at ws+2097152  : 2048*2464*4      = 20185088 B (ends 22282240)
  unsigned short* A_ws = (unsigned short*)(ws + 0);
  float*          Gp   = (float*)         (ws + 2097152L);
  unsigned short* btf  = (unsigned short*)(ws + 406594560L);  // 18874368, ends 425468928
  if (ws_size < 425468928ULL) return;  // fails validation loudly rather than corrupting

  cast_all<<<2048, 256, 0, stream>>>(x, wq, wk, wv, bq, bk, bv, xb, wcat, bcat);

  // QKV: [65536 x 2304] = xb [65536 x 768] * wcat^T, +bcat, bf16 out
  gemm_bt<1><<<dim3(512, 18, 1), 256, 0, stream>>>(
      xb, DD, 0L, wcat, DD, 0L, qkv, 2304, 0L, bcat, DD);

  energy_partial<<<dim3(8, HH, BB), 256, 0, stream>>>(qkv, Gp);
  energy_finish<<<dim3(HH, BB, 1), 256, 0, stream>>>(Gp, tau, A_ws);

  build_btf<<<dim3(6, HH, BB), 256, 0, stream>>>(A_ws, wo, btf);

  // out[b] = V[b] [4096x768] * Btf[b]^T + bo, f32 out
  gemm_bt<0><<<dim3(32, 6, BB), 256, 0, stream>>>(
      qkv + 1536, 2304, (long)NN * 2304, btf, DD, (long)DD * DD,
      d_out, DD, (long)NN * DD, bo, DD);
}

// Round 4
// 841.245 us; speedup vs baseline: 1.4435x; 1.4435x over previous
//
#include <hip/hip_runtime.h>
#include <hip/hip_bf16.h>

typedef __attribute__((ext_vector_type(8))) short bf16x8_t;   // MFMA A/B frag (8 bf16)
typedef __attribute__((ext_vector_type(4))) float f32x4_t;    // MFMA C/D frag
typedef __attribute__((ext_vector_type(4))) float fv4;
typedef __attribute__((ext_vector_type(4))) unsigned short us4_t;
typedef __attribute__((ext_vector_type(8))) unsigned short us8_t;

// Problem constants
static constexpr int BB = 16, NN = 4096, DD = 768, HH = 16, EE = 48;

__device__ __forceinline__ unsigned short f2bf(float f) {
  unsigned int u = __float_as_uint(f);
  u += 0x7fffu + ((u >> 16) & 1u);   // RNE; inputs are finite
  return (unsigned short)(u >> 16);
}

__device__ __forceinline__ void load_lds16(const void* g, void* l) {
  __builtin_amdgcn_global_load_lds((const __attribute__((address_space(1))) void*)g,
                                   (__attribute__((address_space(3))) void*)l, 16, 0, 0);
}

// ---------------------------------------------------------------------------
// K1: cast x -> bf16, {wq,wk,wv} -> wcat bf16 [2304][768], {bq,bk,bv} -> bcat f32
// ---------------------------------------------------------------------------
__global__ __launch_bounds__(256) void cast_all(
    const float* __restrict__ x,
    const float* __restrict__ wq, const float* __restrict__ wk, const float* __restrict__ wv,
    const float* __restrict__ bq, const float* __restrict__ bk, const float* __restrict__ bv,
    unsigned short* __restrict__ xb, unsigned short* __restrict__ wcat, float* __restrict__ bcat)
{
  const long NX4 = (long)BB * NN * DD / 4;       // 12582912 float4 slots
  const long NW4 = 3L * DD * DD / 4;             // 442368
  const long NBS = 3L * DD;                      // 2304
  long stride = (long)gridDim.x * blockDim.x;
  for (long i = (long)blockIdx.x * blockDim.x + threadIdx.x; i < NX4 + NW4 + NBS; i += stride) {
    if (i < NX4) {
      fv4 v = ((const fv4*)x)[i];
      us4_t o; o.x = f2bf(v.x); o.y = f2bf(v.y); o.z = f2bf(v.z); o.w = f2bf(v.w);
      ((us4_t*)xb)[i] = o;
    } else if (i < NX4 + NW4) {
      long w = i - NX4;
      long row = (w * 4) / DD;
      long col = (w * 4) % DD;
      const float* src = (row < DD)     ? (wq + row * DD + col)
                       : (row < 2 * DD) ? (wk + (row - DD) * DD + col)
                                        : (wv + (row - 2 * DD) * DD + col);
      fv4 v = *(const fv4*)src;
      us4_t o; o.x = f2bf(v.x); o.y = f2bf(v.y); o.z = f2bf(v.z); o.w = f2bf(v.w);
      ((us4_t*)wcat)[w] = o;
    } else {
      long j = i - NX4 - NW4;
      bcat[j] = (j < DD) ? bq[j] : (j < 2 * DD) ? bk[j - DD] : bv[j - 2 * DD];
    }
  }
}

// ---------------------------------------------------------------------------
// K2/K5: bf16 GEMM, C[m][n] = sum_k A[m][k] * Bt[n][k] + bias[n]
// 128x128 tile, BK=32, 4 waves (2x2 of 64x64), m97 structure.
// MODE 0: f32 store, row-major [m][n]            (used for final output GEMM)
// MODE 2: QKV split: cols<1536 (Q,K) stored bf16 TRANSPOSED as qkT[b][col][n]
//         (per lane a us4 8-B packed store of 4 consecutive n -> per column a
//         full 128B line per wave); cols>=1536 (V) stored bf16 row-major in
//         Vout[b*4096+n][col-1536]. Transposed Q/K makes the energy kernel's
//         reads contiguous (round-3 lesson: LDS scalar transpose w/ dynamic
//         vector extract = rule-#20 poison, 2000+ VALU instr/chunk).
// ---------------------------------------------------------------------------
template<int MODE>
__global__ __launch_bounds__(256) void gemm_bt(
    const unsigned short* __restrict__ A, int lda, long aStride,
    const unsigned short* __restrict__ Bt, int ldb, long bStride,
    void* __restrict__ Cv, int ldc, long cStride,
    unsigned short* __restrict__ Vout,
    const float* __restrict__ bias, int K)
{
  __shared__ unsigned short As[128 * 32];
  __shared__ unsigned short Bs[128 * 32];
  const int zb = blockIdx.z;
  const unsigned short* Ab = A + (long)zb * aStride;
  const unsigned short* Bb = Bt + (long)zb * bStride;
  const long m0 = (long)blockIdx.x * 128;
  const int n0 = blockIdx.y * 128;
  const int t = threadIdx.x;
  const int wave = t >> 6, lane = t & 63;
  const int wr = wave >> 1, wc = wave & 1;

  f32x4_t acc[4][4] = {};

  // staging geometry: byte offset o in 8KB tile; row = o>>6 (32 bf16 = 64B rows)
  const int o0 = t * 16;
  const int row0 = o0 >> 6, kc0 = (o0 & 63) >> 1;
  const int o1 = 4096 + t * 16;
  const int row1 = o1 >> 6, kc1 = (o1 & 63) >> 1;
  unsigned short* ldsA = As + wave * 512;  // + lane*16B by HW
  unsigned short* ldsB = Bs + wave * 512;

  for (int kt = 0; kt < K; kt += 32) {
    load_lds16(Ab + (m0 + row0) * (long)lda + kt + kc0, ldsA);
    load_lds16(Ab + (m0 + row1) * (long)lda + kt + kc1, ldsA + 2048);
    load_lds16(Bb + (long)(n0 + row0) * ldb + kt + kc0, ldsB);
    load_lds16(Bb + (long)(n0 + row1) * ldb + kt + kc1, ldsB + 2048);
    __syncthreads();
    bf16x8_t af[4], bfr[4];
    const int kofs = (lane >> 4) << 3;
#pragma unroll
    for (int f = 0; f < 4; ++f) {
      af[f]  = *(const bf16x8_t*)&As[(wr * 64 + f * 16 + (lane & 15)) * 32 + kofs];
      bfr[f] = *(const bf16x8_t*)&Bs[(wc * 64 + f * 16 + (lane & 15)) * 32 + kofs];
    }
#pragma unroll
    for (int i = 0; i < 4; ++i)
#pragma unroll
      for (int j = 0; j < 4; ++j)
        acc[i][j] = __builtin_amdgcn_mfma_f32_16x16x32_bf16(af[i], bfr[j], acc[i][j], 0, 0, 0);
    __syncthreads();
  }

  // epilogue: D col = lane&15, row = (lane>>4)*4 + r  (m89-verified layout)
  const int col_l = lane & 15;
  const int rbase = (lane >> 4) << 2;

  if (MODE == 2 && n0 < 1536) {
    // transposed bf16 write: qkT[b][col][n]; acc[i][j][0..3] are 4 consecutive n
    unsigned short* qkT = (unsigned short*)Cv;
    const int bb = (int)(m0 >> 12);          // batch (tiles never straddle: 4096%128==0)
    const int nb = (int)(m0 & 4095) + wr * 64 + rbase;
#pragma unroll
    for (int i = 0; i < 4; ++i) {
#pragma unroll
      for (int j = 0; j < 4; ++j) {
        const int col = n0 + wc * 64 + j * 16 + col_l;
        const float bz = bias[col];
        us4_t o;
#pragma unroll
        for (int r = 0; r < 4; ++r) o[r] = f2bf(acc[i][j][r] + bz);
        *(us4_t*)(qkT + (((long)bb * 1536 + col) << 12) + nb + i * 16) = o;
      }
    }
    return;
  }

#pragma unroll
  for (int i = 0; i < 4; ++i) {
#pragma unroll
    for (int r = 0; r < 4; ++r) {
      const long grow = m0 + wr * 64 + i * 16 + rbase + r;
      if (MODE == 2) {   // V region: row-major bf16 [b*4096+n][768]
        unsigned short* crow = Vout + grow * DD + (n0 - 1536) + wc * 64;
#pragma unroll
        for (int j = 0; j < 4; ++j) {
          int col = j * 16 + col_l;
          crow[col] = f2bf(acc[i][j][r] + bias[n0 + wc * 64 + col]);
        }
      } else {           // MODE 0: f32 row-major
        float* crow = (float*)Cv + (long)zb * cStride + grow * ldc + n0 + wc * 64;
#pragma unroll
        for (int j = 0; j < 4; ++j) {
          int col = j * 16 + col_l;
          crow[col] = acc[i][j][r] + bias[n0 + wc * 64 + col];
        }
      }
    }
  }
}

// ---------------------------------------------------------------------------
// K3a: per (b,h,nc): partial G = Q_h^T K_h over n in [nc*512, nc*512+512)
// via MFMA, plus free diag(Q^TQ), diag(K^TK) partials for the L2 norms.
// Q^T/K^T are read CONTIGUOUSLY from qkT[b][col][n] (written by K2) and
// staged via global_load_lds (zero transpose VALU). LDS tile [48 e][128 n],
// 256B rows, 16B-block XOR swizzle (blk ^= e&7) applied on BOTH the
// pre-swizzled global source and the frag ds_read (rule #21) -> 2-way banks.
// Writes fp32 partials Gp[(b*H+h)*8+nc][2464]:
//   [0..2352) = G (48 rows x stride 49), [2352..2400) nq2, [2400..2448) nk2.
// ---------------------------------------------------------------------------
#define NCH 128
#define GP_STRIDE 2464

__global__ __launch_bounds__(256) void energy_partial(
    const unsigned short* __restrict__ qkT, float* __restrict__ Gp)
{
  __shared__ unsigned short Qs[48 * 128];   // 12288 B
  __shared__ unsigned short Ks[48 * 128];
  __shared__ float G_sh[2448];              // G(49-stride), nq2, nk2

  const int nc = blockIdx.x, h = blockIdx.y, b = blockIdx.z;
  const int t = threadIdx.x;
  const int wave = t >> 6, lane = t & 63;

  for (int i = t; i < 2448; i += 256) G_sh[i] = 0.f;

  f32x4_t accG[3][3] = {};
  f32x4_t accQ[3] = {};
  f32x4_t accK[3] = {};

  // staging source offsets: linear LDS byte L = p*4096 + wave*1024 + lane*16
  // -> e = L>>8, 16B-block blk = (L>>4)&15; inverse-swizzled source n-block
  long qoff[3];
#pragma unroll
  for (int p = 0; p < 3; ++p) {
    const int L = p * 4096 + wave * 1024 + lane * 16;
    const int e = L >> 8;
    const int blk = (L >> 4) & 15;
    const int sblk = blk ^ (e & 7);
    qoff[p] = (long)e * NN + sblk * 8;
  }
  const unsigned short* baseQ = qkT + ((long)b * 1536 + h * 48) * NN;
  const unsigned short* baseK = baseQ + (long)DD * NN;

  // frag read offsets (bytes, swizzled): e = f*16+(lane&15), n-blk = wave*4+(lane>>4)
  int foff[3];
#pragma unroll
  for (int f = 0; f < 3; ++f) {
    const int e = f * 16 + (lane & 15);
    foff[f] = e * 256 + (((wave * 4 + (lane >> 4)) ^ (e & 7)) << 4);
  }
  __syncthreads();

  const int c0 = nc * 512;
  for (int ci = 0; ci < 4; ++ci) {
    const long c = c0 + ci * NCH;
#pragma unroll
    for (int p = 0; p < 3; ++p) {
      load_lds16(baseQ + qoff[p] + c, Qs + p * 2048 + wave * 512);
      load_lds16(baseK + qoff[p] + c, Ks + p * 2048 + wave * 512);
    }
    __syncthreads();
    bf16x8_t aq[3], ak[3];
#pragma unroll
    for (int f = 0; f < 3; ++f) {
      aq[f] = *(const bf16x8_t*)((const char*)Qs + foff[f]);
      ak[f] = *(const bf16x8_t*)((const char*)Ks + foff[f]);
    }
#pragma unroll
    for (int i = 0; i < 3; ++i) {
      accQ[i] = __builtin_amdgcn_mfma_f32_16x16x32_bf16(aq[i], aq[i], accQ[i], 0, 0, 0);
      accK[i] = __builtin_amdgcn_mfma_f32_16x16x32_bf16(ak[i], ak[i], accK[i], 0, 0, 0);
#pragma unroll
      for (int j = 0; j < 3; ++j)
        accG[i][j] = __builtin_amdgcn_mfma_f32_16x16x32_bf16(aq[i], ak[j], accG[i][j], 0, 0, 0);
    }
    __syncthreads();
  }

  // cross-wave reduce G into LDS
#pragma unroll
  for (int i = 0; i < 3; ++i)
#pragma unroll
    for (int j = 0; j < 3; ++j) {
      int e = i * 16 + ((lane >> 4) << 2);
      int qi = j * 16 + (lane & 15);
#pragma unroll
      for (int r = 0; r < 4; ++r) atomicAdd(&G_sh[(e + r) * 49 + qi], accG[i][j][r]);
    }
  // diagonal lanes contribute the sum-of-squares
  if ((lane >> 4) == ((lane & 15) >> 2)) {
    int r = (lane & 15) & 3;
#pragma unroll
    for (int f = 0; f < 3; ++f) {
      atomicAdd(&G_sh[2352 + f * 16 + (lane & 15)], accQ[f][r]);
      atomicAdd(&G_sh[2400 + f * 16 + (lane & 15)], accK[f][r]);
    }
  }
  __syncthreads();

  float* out = Gp + (long)(((b * HH + h) << 3) + nc) * GP_STRIDE;
  for (int i = t; i < 2448; i += 256) out[i] = G_sh[i];
}

// ---------------------------------------------------------------------------
// K3b: per (b,h): reduce the 8 partials, norms, softmax, /tau. Writes A as
// bf16 padded [48][64] (cols 48..63 zero) for the MFMA consumer in K4.
// ---------------------------------------------------------------------------
__global__ __launch_bounds__(256) void energy_finish(
    const float* __restrict__ Gp, const float* __restrict__ tau_p,
    unsigned short* __restrict__ A_out)
{
  __shared__ float G_sh[2448];
  const int h = blockIdx.x, b = blockIdx.y;
  const int t = threadIdx.x;

  const float* base = Gp + (long)((b * HH + h) << 3) * GP_STRIDE;
  for (int i = t; i < 2448; i += 256) {
    float s = 0.f;
#pragma unroll
    for (int nc = 0; nc < 8; ++nc) s += base[(long)nc * GP_STRIDE + i];
    G_sh[i] = s;
  }
  __syncthreads();

  if (t < 48) {
    const float tau = *tau_p;
    const float nq = fmaxf(sqrtf(G_sh[2352 + t]), 1e-12f);
    float row[48];
    float mx = -1e30f;
#pragma unroll 1
    for (int qi = 0; qi < 48; ++qi) {
      float nk = fmaxf(sqrtf(G_sh[2400 + qi]), 1e-12f);
      float g = G_sh[t * 49 + qi] / (nq * nk);
      row[qi] = g; mx = fmaxf(mx, g);
    }
    float s = 0.f;
#pragma unroll 1
    for (int qi = 0; qi < 48; ++qi) { row[qi] = __expf(row[qi] - mx); s += row[qi]; }
    const float inv = 1.f / (s * tau);
    unsigned short* dst = A_out + (((long)b * HH + h) * 48) * 64 + (long)t * 64;
#pragma unroll 1
    for (int qi = 0; qi < 48; ++qi) dst[qi] = f2bf(row[qi] * inv);
#pragma unroll 1
    for (int qi = 48; qi < 64; ++qi) dst[qi] = 0;
  }
}

// ---------------------------------------------------------------------------
// K4: Btf[b][no][h*48+e] = sum_qi A_h[e][qi] * wo[no][h*48+qi]   (MFMA, K=48
// padded to 64). A-operand = wo rows (qi-contiguous), B-operand = A_h rows.
// ---------------------------------------------------------------------------
__global__ __launch_bounds__(256) void build_btf(
    const unsigned short* __restrict__ A_ws, const float* __restrict__ wo,
    unsigned short* __restrict__ btf)
{
  __shared__ unsigned short Wsh[128 * 72];
  __shared__ unsigned short Ash[48 * 72];
  const int nchunk = blockIdx.x, h = blockIdx.y, b = blockIdx.z;
  const int t = threadIdx.x;
  const int wave = t >> 6, lane = t & 63;
  const int no0 = nchunk * 128;

  for (int i = t; i < 128 * 64; i += 256) {
    int r = i >> 6, c = i & 63;
    Wsh[r * 72 + c] = (c < 48) ? f2bf(wo[(long)(no0 + r) * DD + h * 48 + c]) : (unsigned short)0;
  }
  const unsigned short* Asrc = A_ws + ((long)b * HH + h) * 48 * 64;
  for (int i = t; i < 48 * 64; i += 256) {
    int r = i >> 6, c = i & 63;
    Ash[r * 72 + c] = Asrc[r * 64 + c];   // already zero-padded in cols 48..63
  }
  __syncthreads();

  f32x4_t acc[2][3] = {};
#pragma unroll
  for (int ks = 0; ks < 2; ++ks) {
    const int k0 = ks * 32 + ((lane >> 4) << 3);
    bf16x8_t af[2], bfr[3];
#pragma unroll
    for (int mi = 0; mi < 2; ++mi)
      af[mi] = *(const bf16x8_t*)&Wsh[(wave * 32 + mi * 16 + (lane & 15)) * 72 + k0];
#pragma unroll
    for (int nj = 0; nj < 3; ++nj)
      bfr[nj] = *(const bf16x8_t*)&Ash[(nj * 16 + (lane & 15)) * 72 + k0];
#pragma unroll
    for (int mi = 0; mi < 2; ++mi)
#pragma unroll
      for (int nj = 0; nj < 3; ++nj)
        acc[mi][nj] = __builtin_amdgcn_mfma_f32_16x16x32_bf16(af[mi], bfr[nj], acc[mi][nj], 0, 0, 0);
  }

  const int col_l = lane & 15;
  const int rbase = (lane >> 4) << 2;
#pragma unroll
  for (int mi = 0; mi < 2; ++mi)
#pragma unroll
    for (int r = 0; r < 4; ++r) {
      int no = no0 + wave * 32 + mi * 16 + rbase + r;
      unsigned short* dst = btf + ((long)b * DD + no) * DD + h * 48;
#pragma unroll
      for (int nj = 0; nj < 3; ++nj)
        dst[nj * 16 + col_l] = f2bf(acc[mi][nj][r]);
    }
}

// ---------------------------------------------------------------------------
extern "C" void kernel_launch(void* const* d_in, const int* in_sizes, int n_in,
                              void* d_out, int out_size, void* d_ws, size_t ws_size,
                              hipStream_t stream)
{
  (void)in_sizes; (void)n_in; (void)out_size;
  const float* x   = (const float*)d_in[0];
  const float* wq  = (const float*)d_in[1];
  const float* bq  = (const float*)d_in[2];
  const float* wk  = (const float*)d_in[3];
  const float* bk  = (const float*)d_in[4];
  const float* wv  = (const float*)d_in[5];
  const float* bv  = (const float*)d_in[6];
  const float* wo  = (const float*)d_in[7];
  const float* bo  = (const float*)d_in[8];
  const float* tau = (const float*)d_in[9];

  char* ws = (char*)d_ws;
  // layout (bytes)
  unsigned short* xb    = (unsigned short*)(ws + 0);           // 100663296 (dead after K2)
  unsigned short* qkT   = (unsigned short*)(ws + 100663296L);  // 16*1536*4096*2 = 201326592
  unsigned short* v_buf = (unsigned short*)(ws + 301989888L);  // 16*4096*768*2 = 100663296
  unsigned short* wcat  = (unsigned short*)(ws + 402653184L);  // 3538944
  float*          bcat  = (float*)         (ws + 406192128L);  // 9216
  // Aliases into the dead xb region (xb only read by K2; K3a/K3b/K4 are
  // stream-ordered after it):
  unsigned short* A_ws = (unsigned short*)(ws + 0);            // 1572864
  float*          Gp   = (float*)         (ws + 2097152L);     // 2048*2464*4 = 20185088
  unsigned short* btf  = (unsigned short*)(ws + 406594560L);   // 18874368, ends 425468928
  if (ws_size < 425468928ULL) return;  // fails validation loudly rather than corrupting

  cast_all<<<2048, 256, 0, stream>>>(x, wq, wk, wv, bq, bk, bv, xb, wcat, bcat);

  // QKV: [65536 x 2304] = xb * wcat^T + bcat; Q,K -> qkT (transposed), V -> v_buf
  gemm_bt<2><<<dim3(512, 18, 1), 256, 0, stream>>>(
      xb, DD, 0L, wcat, DD, 0L, qkT, 0, 0L, v_buf, bcat, DD);

  energy_partial<<<dim3(8, HH, BB), 256, 0, stream>>>(qkT, Gp);
  energy_finish<<<dim3(HH, BB, 1), 256, 0, stream>>>(Gp, tau, A_ws);

  build_btf<<<dim3(6, HH, BB), 256, 0, stream>>>(A_ws, wo, btf);

  // out[b] = V[b] [4096x768] * Btf[b]^T + bo, f32 out
  gemm_bt<0><<<dim3(32, 6, BB), 256, 0, stream>>>(
      v_buf, DD, (long)NN * DD, btf, DD, (long)DD * DD,
      d_out, DD, (long)NN * DD, nullptr, bo, DD);
}

// Round 5
// 561.675 us; speedup vs baseline: 2.1619x; 1.4977x over previous
//
#include <hip/hip_runtime.h>
#include <hip/hip_bf16.h>

typedef __attribute__((ext_vector_type(8))) short bf16x8_t;   // MFMA A/B frag (8 bf16)
typedef __attribute__((ext_vector_type(4))) float f32x4_t;    // MFMA C/D frag
typedef __attribute__((ext_vector_type(4))) float fv4;
typedef __attribute__((ext_vector_type(4))) unsigned short us4_t;
typedef __attribute__((ext_vector_type(8))) unsigned short us8_t;

// Problem constants
static constexpr int BB = 16, NN = 4096, DD = 768, HH = 16, EE = 48;

__device__ __forceinline__ unsigned short f2bf(float f) {
  unsigned int u = __float_as_uint(f);
  u += 0x7fffu + ((u >> 16) & 1u);   // RNE; inputs are finite
  return (unsigned short)(u >> 16);
}
__device__ __forceinline__ float bf2f(unsigned short s) {
  unsigned int u = ((unsigned int)s) << 16;
  return __uint_as_float(u);
}

__device__ __forceinline__ void load_lds16(const void* g, void* l) {
  __builtin_amdgcn_global_load_lds((const __attribute__((address_space(1))) void*)g,
                                   (__attribute__((address_space(3))) void*)l, 16, 0, 0);
}

// ---------------------------------------------------------------------------
// 64x64 f32->bf16 transposing tile cast via LDS. dst[c][r] = src[r][c].
// Optional pass-through row-major bf16 write (thru).
// ---------------------------------------------------------------------------
template<int WRITE_THRU>
__device__ __forceinline__ void tcast64(const float* __restrict__ src, int sld,
                                        unsigned short* __restrict__ dst, int dld,
                                        unsigned short* __restrict__ thru, int tld, int t)
{
  __shared__ float L[64][65];
#pragma unroll
  for (int q = 0; q < 4; ++q) {
    const int fi = t + q * 256;          // 0..1023
    const int r = fi >> 4, c4 = fi & 15; // row, col-group of 4
    fv4 v = *(const fv4*)(src + (long)r * sld + c4 * 4);
    L[r][c4 * 4 + 0] = v.x; L[r][c4 * 4 + 1] = v.y;
    L[r][c4 * 4 + 2] = v.z; L[r][c4 * 4 + 3] = v.w;
    if (WRITE_THRU) {
      us4_t o; o.x = f2bf(v.x); o.y = f2bf(v.y); o.z = f2bf(v.z); o.w = f2bf(v.w);
      *(us4_t*)(thru + (long)r * tld + c4 * 4) = o;
    }
  }
  __syncthreads();
#pragma unroll
  for (int q = 0; q < 2; ++q) {
    const int wi = t + q * 256;          // 0..511
    const int rr = wi >> 3, ng = wi & 7; // dst row, 8-col group
    us8_t o;
#pragma unroll
    for (int j = 0; j < 8; ++j) o[j] = f2bf(L[ng * 8 + j][rr]);
    *(us8_t*)(dst + (long)rr * dld + ng * 8) = o;
  }
  __syncthreads();
}

// K1a: x -> xb (row-major bf16) AND xbT (transposed bf16 [b][d][n])
__global__ __launch_bounds__(256) void transpose_cast_x(
    const float* __restrict__ x, unsigned short* __restrict__ xb,
    unsigned short* __restrict__ xbT)
{
  const int nx = blockIdx.x, dx = blockIdx.y, b = blockIdx.z;
  const int n0 = nx * 64, d0 = dx * 64;
  const float* src = x + ((long)b * NN + n0) * DD + d0;
  unsigned short* thru = xb + ((long)b * NN + n0) * DD + d0;
  unsigned short* dst = xbT + ((long)b * DD + d0) * NN + n0;
  tcast64<1>(src, DD, dst, NN, thru, DD, threadIdx.x);
}

// K1b: W2=[wq;wk] bf16 [1536][768]; wvT bf16 [768(k)][768(i)] = wv^T; zeros
__global__ __launch_bounds__(256) void small_cast(
    const float* __restrict__ wq, const float* __restrict__ wk, const float* __restrict__ wv,
    unsigned short* __restrict__ W2, unsigned short* __restrict__ wvT,
    float* __restrict__ zeros)
{
  const int blk = blockIdx.x, t = threadIdx.x;
  if (blk < 576) {
    // 1536x768 = 1179648 elems = 576 blocks * 512 fv4-ish groups
#pragma unroll
    for (int q = 0; q < 2; ++q) {
      long g = (long)blk * 512 + t * 2 + q;   // fv4 index
      long e0 = g * 4;
      int row = (int)(e0 / DD), col = (int)(e0 % DD);
      const float* src = (row < DD) ? (wq + (long)row * DD + col)
                                    : (wk + (long)(row - DD) * DD + col);
      fv4 v = *(const fv4*)src;
      us4_t o; o.x = f2bf(v.x); o.y = f2bf(v.y); o.z = f2bf(v.z); o.w = f2bf(v.w);
      *(us4_t*)(W2 + e0) = o;
    }
  } else if (blk < 720) {
    const int tile = blk - 576;
    const int ti = tile / 12, tj = tile % 12;  // k-block, i-block
    const int k0 = ti * 64, i0 = tj * 64;
    // wvT[k][i] = wv[i][k]
    tcast64<0>(wv + (long)i0 * DD + k0, DD, wvT + (long)k0 * DD + i0, DD, nullptr, 0, t);
  } else {
#pragma unroll
    for (int q = 0; q < 4; ++q) zeros[t * 4 + q] = 0.f;
  }
}

// K1c: xsum[b][d] = sum_n x[b][n][d], read from xbT rows (contiguous).
__global__ __launch_bounds__(256) void colsum(
    const unsigned short* __restrict__ xbT, float* __restrict__ xsum)
{
  const int bx = blockIdx.x, b = blockIdx.y;
  const int wave = threadIdx.x >> 6, lane = threadIdx.x & 63;
  const int d = bx * 4 + wave;
  const unsigned short* row = xbT + ((long)b * DD + d) * NN;
  float s = 0.f;
#pragma unroll
  for (int it = 0; it < 8; ++it) {
    us8_t v = *(const us8_t*)(row + (it * 64 + lane) * 8);
#pragma unroll
    for (int j = 0; j < 8; ++j) s += bf2f(v[j]);
  }
#pragma unroll
  for (int off = 32; off > 0; off >>= 1) s += __shfl_down(s, off);
  if (lane == 0) xsum[(long)b * DD + d] = s;
}

// ---------------------------------------------------------------------------
// bf16 GEMM, C[m][n] = sum_k A[m][k] * Bt[n][k] + bias[n]  (per-z bias optional)
// 128x128 tile, BK=32, 4 waves (2x2 of 64x64), m97 structure.
// OUT_BF16=1 -> bf16 store, else f32 store.
// ---------------------------------------------------------------------------
template<int OUT_BF16>
__global__ __launch_bounds__(256) void gemm_bt(
    const unsigned short* __restrict__ A, int lda, long aStride,
    const unsigned short* __restrict__ Bt, int ldb, long bStride,
    void* __restrict__ Cv, int ldc, long cStride,
    const float* __restrict__ bias, long biasStride, int K)
{
  __shared__ unsigned short As[128 * 32];
  __shared__ unsigned short Bs[128 * 32];
  const int zb = blockIdx.z;
  const unsigned short* Ab = A + (long)zb * aStride;
  const unsigned short* Bb = Bt + (long)zb * bStride;
  const float* bz = bias + (long)zb * biasStride;
  const long m0 = (long)blockIdx.x * 128;
  const int n0 = blockIdx.y * 128;
  const int t = threadIdx.x;
  const int wave = t >> 6, lane = t & 63;
  const int wr = wave >> 1, wc = wave & 1;

  f32x4_t acc[4][4] = {};

  // staging geometry: byte offset o in 8KB tile; row = o>>6 (32 bf16 = 64B rows)
  const int o0 = t * 16;
  const int row0 = o0 >> 6, kc0 = (o0 & 63) >> 1;
  const int o1 = 4096 + t * 16;
  const int row1 = o1 >> 6, kc1 = (o1 & 63) >> 1;
  unsigned short* ldsA = As + wave * 512;  // + lane*16B by HW
  unsigned short* ldsB = Bs + wave * 512;

  for (int kt = 0; kt < K; kt += 32) {
    load_lds16(Ab + (m0 + row0) * (long)lda + kt + kc0, ldsA);
    load_lds16(Ab + (m0 + row1) * (long)lda + kt + kc1, ldsA + 2048);
    load_lds16(Bb + (long)(n0 + row0) * ldb + kt + kc0, ldsB);
    load_lds16(Bb + (long)(n0 + row1) * ldb + kt + kc1, ldsB + 2048);
    __syncthreads();
    bf16x8_t af[4], bfr[4];
    const int kofs = (lane >> 4) << 3;
#pragma unroll
    for (int f = 0; f < 4; ++f) {
      af[f]  = *(const bf16x8_t*)&As[(wr * 64 + f * 16 + (lane & 15)) * 32 + kofs];
      bfr[f] = *(const bf16x8_t*)&Bs[(wc * 64 + f * 16 + (lane & 15)) * 32 + kofs];
    }
#pragma unroll
    for (int i = 0; i < 4; ++i)
#pragma unroll
      for (int j = 0; j < 4; ++j)
        acc[i][j] = __builtin_amdgcn_mfma_f32_16x16x32_bf16(af[i], bfr[j], acc[i][j], 0, 0, 0);
    __syncthreads();
  }

  // epilogue: D col = lane&15, row = (lane>>4)*4 + r  (m89-verified layout)
  const int col_l = lane & 15;
  const int rbase = (lane >> 4) << 2;
#pragma unroll
  for (int i = 0; i < 4; ++i) {
#pragma unroll
    for (int r = 0; r < 4; ++r) {
      const long grow = m0 + wr * 64 + i * 16 + rbase + r;
      if (OUT_BF16) {
        unsigned short* crow = (unsigned short*)Cv + (long)zb * cStride + grow * ldc + n0 + wc * 64;
#pragma unroll
        for (int j = 0; j < 4; ++j) {
          int col = j * 16 + col_l;
          crow[col] = f2bf(acc[i][j][r] + bz[n0 + wc * 64 + col]);
        }
      } else {
        float* crow = (float*)Cv + (long)zb * cStride + grow * ldc + n0 + wc * 64;
#pragma unroll
        for (int j = 0; j < 4; ++j) {
          int col = j * 16 + col_l;
          crow[col] = acc[i][j][r] + bz[n0 + wc * 64 + col];
        }
      }
    }
  }
}

// ---------------------------------------------------------------------------
// K3a: per (b,h,kc): partial E_h = Tq_h * wk_h^T over k' in [kc*384,+384),
// plus diag(Tq_h*wq_h^T) -> nq2, diag(Tk_h*wk_h^T) -> nk2 (MFMA diag trick).
// Tq_h = T[b] rows [h*48,+48), Tk_h = rows [768+h*48,+48); same for W2.
// Staged via global_load_lds with the round-4-proven 16B-block XOR swizzle
// (pre-swizzled global source + swizzled frag reads; rows 256B).
// Writes fp32 partials Gp[((b*H+h)*2+kc)][2464]:
//   [0..2352) = E (48 rows x stride 49), [2352..2400) nq2, [2400..2448) nk2.
// ---------------------------------------------------------------------------
#define GP_STRIDE 2464

__global__ __launch_bounds__(256) void energy_partial2(
    const unsigned short* __restrict__ T, const unsigned short* __restrict__ W2,
    float* __restrict__ Gp)
{
  __shared__ unsigned short Ts[2][48 * 128];   // Tq, Tk tiles (12KB each)
  __shared__ unsigned short Ws[2][48 * 128];   // wq, wk tiles
  __shared__ float G_sh[2448];

  const int kc = blockIdx.x, h = blockIdx.y, b = blockIdx.z;
  const int t = threadIdx.x;
  const int wave = t >> 6, lane = t & 63;

  for (int i = t; i < 2448; i += 256) G_sh[i] = 0.f;

  f32x4_t accG[3][3] = {};
  f32x4_t accQ[3] = {};
  f32x4_t accK[3] = {};

  // staging source offsets: linear LDS byte L = p*4096 + wave*1024 + lane*16
  // -> e = L>>8, 16B-block blk = (L>>4)&15; inverse-swizzled source k-block
  long qoff[3];
#pragma unroll
  for (int p = 0; p < 3; ++p) {
    const int L = p * 4096 + wave * 1024 + lane * 16;
    const int e = L >> 8;
    const int blk = (L >> 4) & 15;
    const int sblk = blk ^ (e & 7);
    qoff[p] = (long)e * DD + sblk * 8;
  }
  const unsigned short* Tq = T + ((long)b * 1536 + h * 48) * DD;
  const unsigned short* Tk = Tq + (long)DD * DD;
  const unsigned short* Wq = W2 + (long)h * 48 * DD;
  const unsigned short* Wk = Wq + (long)DD * DD;

  // frag read offsets (bytes, swizzled): e = f*16+(lane&15), k-blk = wave*4+(lane>>4)
  int foff[3];
#pragma unroll
  for (int f = 0; f < 3; ++f) {
    const int e = f * 16 + (lane & 15);
    foff[f] = e * 256 + (((wave * 4 + (lane >> 4)) ^ (e & 7)) << 4);
  }
  __syncthreads();

  for (int ci = 0; ci < 3; ++ci) {
    const int col0 = kc * 384 + ci * 128;
#pragma unroll
    for (int p = 0; p < 3; ++p) {
      load_lds16(Tq + qoff[p] + col0, &Ts[0][p * 2048] + wave * 512);
      load_lds16(Tk + qoff[p] + col0, &Ts[1][p * 2048] + wave * 512);
      load_lds16(Wq + qoff[p] + col0, &Ws[0][p * 2048] + wave * 512);
      load_lds16(Wk + qoff[p] + col0, &Ws[1][p * 2048] + wave * 512);
    }
    __syncthreads();
    bf16x8_t tq[3], tk[3], wqf[3], wkf[3];
#pragma unroll
    for (int f = 0; f < 3; ++f) {
      tq[f]  = *(const bf16x8_t*)((const char*)&Ts[0][0] + foff[f]);
      tk[f]  = *(const bf16x8_t*)((const char*)&Ts[1][0] + foff[f]);
      wqf[f] = *(const bf16x8_t*)((const char*)&Ws[0][0] + foff[f]);
      wkf[f] = *(const bf16x8_t*)((const char*)&Ws[1][0] + foff[f]);
    }
#pragma unroll
    for (int i = 0; i < 3; ++i) {
      accQ[i] = __builtin_amdgcn_mfma_f32_16x16x32_bf16(tq[i], wqf[i], accQ[i], 0, 0, 0);
      accK[i] = __builtin_amdgcn_mfma_f32_16x16x32_bf16(tk[i], wkf[i], accK[i], 0, 0, 0);
#pragma unroll
      for (int j = 0; j < 3; ++j)
        accG[i][j] = __builtin_amdgcn_mfma_f32_16x16x32_bf16(tq[i], wkf[j], accG[i][j], 0, 0, 0);
    }
    __syncthreads();
  }

  // cross-wave reduce into LDS
#pragma unroll
  for (int i = 0; i < 3; ++i)
#pragma unroll
    for (int j = 0; j < 3; ++j) {
      int e = i * 16 + ((lane >> 4) << 2);
      int qi = j * 16 + (lane & 15);
#pragma unroll
      for (int r = 0; r < 4; ++r) atomicAdd(&G_sh[(e + r) * 49 + qi], accG[i][j][r]);
    }
  // diagonal lanes contribute the norms
  if ((lane >> 4) == ((lane & 15) >> 2)) {
    int r = (lane & 15) & 3;
#pragma unroll
    for (int f = 0; f < 3; ++f) {
      atomicAdd(&G_sh[2352 + f * 16 + (lane & 15)], accQ[f][r]);
      atomicAdd(&G_sh[2400 + f * 16 + (lane & 15)], accK[f][r]);
    }
  }
  __syncthreads();

  float* out = Gp + (long)(((b * HH + h) << 1) + kc) * GP_STRIDE;
  for (int i = t; i < 2448; i += 256) out[i] = G_sh[i];
}

// ---------------------------------------------------------------------------
// K3b: per (b,h): reduce 2 partials, apply bias corrections (exact-zero-cost
// when bq=bk=0: runtime check skips them), norms, softmax, /tau.
// Writes A bf16 padded [48][64] (cols 48..63 zero) for build_btf.
// ---------------------------------------------------------------------------
__global__ __launch_bounds__(256) void energy_finish2(
    const float* __restrict__ Gp, const float* __restrict__ xsum,
    const float* __restrict__ wq, const float* __restrict__ wk,
    const float* __restrict__ bq, const float* __restrict__ bk,
    const float* __restrict__ tau_p, unsigned short* __restrict__ A_out)
{
  __shared__ float G_sh[2448];
  __shared__ float vq[48], vk[48], bqs[48], bks[48];
  __shared__ int has_bias;
  const int h = blockIdx.x, b = blockIdx.y;
  const int t = threadIdx.x;

  const float* base = Gp + (long)((b * HH + h) << 1) * GP_STRIDE;
  for (int i = t; i < 2448; i += 256)
    G_sh[i] = base[i] + base[GP_STRIDE + i];
  if (t < 48) { bqs[t] = bq[h * 48 + t]; bks[t] = bk[h * 48 + t]; }
  __syncthreads();
  if (t == 0) {
    float s = 0.f;
    for (int i = 0; i < 48; ++i) s += fabsf(bqs[i]) + fabsf(bks[i]);
    has_bias = (s != 0.f);
  }
  __syncthreads();
  if (has_bias) {
    // vq[e] = wq_h[e,:] . xsum[b],  vk[q] = wk_h[q,:] . xsum[b]
    if (t < 96) {
      const int e = t < 48 ? t : t - 48;
      const float* wrow = (t < 48 ? wq : wk) + (long)(h * 48 + e) * DD;
      const float* xs = xsum + (long)b * DD;
      float s = 0.f;
      for (int g = 0; g < DD / 4; ++g) {
        fv4 a = *(const fv4*)(wrow + g * 4);
        fv4 c = *(const fv4*)(xs + g * 4);
        s += a.x * c.x + a.y * c.y + a.z * c.z + a.w * c.w;
      }
      if (t < 48) vq[e] = s; else vk[e] = s;
    }
  } else if (t < 48) { vq[t] = 0.f; vk[t] = 0.f; }
  __syncthreads();

  if (t < 48) {
    const float tau = *tau_p;
    const float nq2c = G_sh[2352 + t] + 2.f * bqs[t] * vq[t] + (float)NN * bqs[t] * bqs[t];
    const float nq = fmaxf(sqrtf(nq2c), 1e-12f);
    float row[48];
    float mx = -1e30f;
#pragma unroll 1
    for (int qi = 0; qi < 48; ++qi) {
      float nk2c = G_sh[2400 + qi] + 2.f * bks[qi] * vk[qi] + (float)NN * bks[qi] * bks[qi];
      float nk = fmaxf(sqrtf(nk2c), 1e-12f);
      float e = G_sh[t * 49 + qi] + vq[t] * bks[qi] + bqs[t] * vk[qi]
              + (float)NN * bqs[t] * bks[qi];
      float g = e / (nq * nk);
      row[qi] = g; mx = fmaxf(mx, g);
    }
    float s = 0.f;
#pragma unroll 1
    for (int qi = 0; qi < 48; ++qi) { row[qi] = __expf(row[qi] - mx); s += row[qi]; }
    const float inv = 1.f / (s * tau);
    unsigned short* dst = A_out + (((long)b * HH + h) * 48) * 64 + (long)t * 64;
#pragma unroll 1
    for (int qi = 0; qi < 48; ++qi) dst[qi] = f2bf(row[qi] * inv);
#pragma unroll 1
    for (int qi = 48; qi < 64; ++qi) dst[qi] = 0;
  }
}

// ---------------------------------------------------------------------------
// K4: Btf[b][no][h*48+e] = sum_qi A_h[e][qi] * wo[no][h*48+qi]   (MFMA, K=48
// padded to 64). A-operand = wo rows (qi-contiguous), B-operand = A_h rows.
// ---------------------------------------------------------------------------
__global__ __launch_bounds__(256) void build_btf(
    const unsigned short* __restrict__ A_ws, const float* __restrict__ wo,
    unsigned short* __restrict__ btf)
{
  __shared__ unsigned short Wsh[128 * 72];
  __shared__ unsigned short Ash[48 * 72];
  const int nchunk = blockIdx.x, h = blockIdx.y, b = blockIdx.z;
  const int t = threadIdx.x;
  const int wave = t >> 6, lane = t & 63;
  const int no0 = nchunk * 128;

  for (int i = t; i < 128 * 64; i += 256) {
    int r = i >> 6, c = i & 63;
    Wsh[r * 72 + c] = (c < 48) ? f2bf(wo[(long)(no0 + r) * DD + h * 48 + c]) : (unsigned short)0;
  }
  const unsigned short* Asrc = A_ws + ((long)b * HH + h) * 48 * 64;
  for (int i = t; i < 48 * 64; i += 256) {
    int r = i >> 6, c = i & 63;
    Ash[r * 72 + c] = Asrc[r * 64 + c];   // already zero-padded in cols 48..63
  }
  __syncthreads();

  f32x4_t acc[2][3] = {};
#pragma unroll
  for (int ks = 0; ks < 2; ++ks) {
    const int k0 = ks * 32 + ((lane >> 4) << 3);
    bf16x8_t af[2], bfr[3];
#pragma unroll
    for (int mi = 0; mi < 2; ++mi)
      af[mi] = *(const bf16x8_t*)&Wsh[(wave * 32 + mi * 16 + (lane & 15)) * 72 + k0];
#pragma unroll
    for (int nj = 0; nj < 3; ++nj)
      bfr[nj] = *(const bf16x8_t*)&Ash[(nj * 16 + (lane & 15)) * 72 + k0];
#pragma unroll
    for (int mi = 0; mi < 2; ++mi)
#pragma unroll
      for (int nj = 0; nj < 3; ++nj)
        acc[mi][nj] = __builtin_amdgcn_mfma_f32_16x16x32_bf16(af[mi], bfr[nj], acc[mi][nj], 0, 0, 0);
  }

  const int col_l = lane & 15;
  const int rbase = (lane >> 4) << 2;
#pragma unroll
  for (int mi = 0; mi < 2; ++mi)
#pragma unroll
    for (int r = 0; r < 4; ++r) {
      int no = no0 + wave * 32 + mi * 16 + rbase + r;
      unsigned short* dst = btf + ((long)b * DD + no) * DD + h * 48;
#pragma unroll
      for (int nj = 0; nj < 3; ++nj)
        dst[nj * 16 + col_l] = f2bf(acc[mi][nj][r]);
    }
}

// ---------------------------------------------------------------------------
// K5: bias2[b][j] = bo[j] + sum_i bv[i]*Btf[b][j][i]
// ---------------------------------------------------------------------------
__global__ __launch_bounds__(256) void build_bias2(
    const unsigned short* __restrict__ btf, const float* __restrict__ bv,
    const float* __restrict__ bo, float* __restrict__ bias2)
{
  const int bx = blockIdx.x, b = blockIdx.y;
  const int wave = threadIdx.x >> 6, lane = threadIdx.x & 63;
  const int j = bx * 4 + wave;
  const unsigned short* row = btf + ((long)b * DD + j) * DD;
  float s = 0.f;
#pragma unroll
  for (int ii = 0; ii < 12; ++ii) {
    int i = ii * 64 + lane;
    s += bf2f(row[i]) * bv[i];
  }
#pragma unroll
  for (int off = 32; off > 0; off >>= 1) s += __shfl_down(s, off);
  if (lane == 0) bias2[(long)b * DD + j] = bo[j] + s;
}

// ---------------------------------------------------------------------------
extern "C" void kernel_launch(void* const* d_in, const int* in_sizes, int n_in,
                              void* d_out, int out_size, void* d_ws, size_t ws_size,
                              hipStream_t stream)
{
  (void)in_sizes; (void)n_in; (void)out_size;
  const float* x   = (const float*)d_in[0];
  const float* wq  = (const float*)d_in[1];
  const float* bq  = (const float*)d_in[2];
  const float* wk  = (const float*)d_in[3];
  const float* bk  = (const float*)d_in[4];
  const float* wv  = (const float*)d_in[5];
  const float* bv  = (const float*)d_in[6];
  const float* wo  = (const float*)d_in[7];
  const float* bo  = (const float*)d_in[8];
  const float* tau = (const float*)d_in[9];

  char* ws = (char*)d_ws;
  // layout (bytes) — no aliasing needed (306 MB total < proven ws >= 425 MB)
  unsigned short* xb    = (unsigned short*)(ws + 0L);          // 100663296
  unsigned short* xbT   = (unsigned short*)(ws + 100663296L);  // 100663296
  unsigned short* S     = (unsigned short*)(ws + 201326592L);  // 16*768*768*2 = 18874368
  unsigned short* T     = (unsigned short*)(ws + 220200960L);  // 16*1536*768*2 = 37748736
  unsigned short* W2    = (unsigned short*)(ws + 257949696L);  // 2359296
  unsigned short* wvT   = (unsigned short*)(ws + 260308992L);  // 1179648
  float*          zeros = (float*)         (ws + 261488640L);  // 4096
  float*          xsum  = (float*)         (ws + 261492736L);  // 49152
  float*          Gp    = (float*)         (ws + 261541888L);  // 512*2464*4 = 5046272
  unsigned short* A_ws  = (unsigned short*)(ws + 266588160L);  // 1572864
  unsigned short* btf   = (unsigned short*)(ws + 268161024L);  // 18874368
  unsigned short* Ctf   = (unsigned short*)(ws + 287035392L);  // 18874368
  float*          bias2 = (float*)         (ws + 305909760L);  // 49152 -> ends 305958912
  if (ws_size < 305958912ULL) return;

  transpose_cast_x<<<dim3(64, 12, BB), 256, 0, stream>>>(x, xb, xbT);
  small_cast<<<721, 256, 0, stream>>>(wq, wk, wv, W2, wvT, zeros);
  colsum<<<dim3(192, BB), 256, 0, stream>>>(xbT, xsum);

  // S[b] = x[b]^T x[b]  (768x768, K=4096), bf16 out
  gemm_bt<1><<<dim3(6, 6, BB), 256, 0, stream>>>(
      xbT, NN, (long)DD * NN, xbT, NN, (long)DD * NN,
      S, DD, (long)DD * DD, zeros, 0L, NN);

  // T[b] = W2 * S[b]  (1536x768, K=768; S symmetric -> Bt=S), bf16 out
  gemm_bt<1><<<dim3(12, 6, BB), 256, 0, stream>>>(
      W2, DD, 0L, S, DD, (long)DD * DD,
      T, DD, (long)1536 * DD, zeros, 0L, DD);

  energy_partial2<<<dim3(2, HH, BB), 256, 0, stream>>>(T, W2, Gp);
  energy_finish2<<<dim3(HH, BB), 256, 0, stream>>>(Gp, xsum, wq, wk, bq, bk, tau, A_ws);

  build_btf<<<dim3(6, HH, BB), 256, 0, stream>>>(A_ws, wo, btf);
  build_bias2<<<dim3(192, BB), 256, 0, stream>>>(btf, bv, bo, bias2);

  // Ctf[b] = Btf[b] * wv  (768x768, K=768), bf16 out
  gemm_bt<1><<<dim3(6, 6, BB), 256, 0, stream>>>(
      btf, DD, (long)DD * DD, wvT, DD, 0L,
      Ctf, DD, (long)DD * DD, zeros, 0L, DD);

  // out[b] = x[b] * Ctf[b]^T + bias2[b]  (4096x768, K=768), f32 out
  gemm_bt<0><<<dim3(32, 6, BB), 256, 0, stream>>>(
      xb, DD, (long)NN * DD, Ctf, DD, (long)DD * DD,
      d_out, DD, (long)NN * DD, bias2, (long)DD, DD);
}

// Round 6
// 509.684 us; speedup vs baseline: 2.3825x; 1.1020x over previous
//
#include <hip/hip_runtime.h>
#include <hip/hip_bf16.h>

typedef __attribute__((ext_vector_type(8))) short bf16x8_t;   // MFMA A/B frag (8 bf16)
typedef __attribute__((ext_vector_type(4))) float f32x4_t;    // MFMA C/D frag
typedef __attribute__((ext_vector_type(4))) float fv4;
typedef __attribute__((ext_vector_type(4))) unsigned short us4_t;
typedef __attribute__((ext_vector_type(8))) unsigned short us8_t;

// Problem constants
static constexpr int BB = 16, NN = 4096, DD = 768, HH = 16, EE = 48;

__device__ __forceinline__ unsigned short f2bf(float f) {
  unsigned int u = __float_as_uint(f);
  u += 0x7fffu + ((u >> 16) & 1u);   // RNE; inputs are finite
  return (unsigned short)(u >> 16);
}
__device__ __forceinline__ float bf2f(unsigned short s) {
  unsigned int u = ((unsigned int)s) << 16;
  return __uint_as_float(u);
}

__device__ __forceinline__ void load_lds16(const void* g, void* l) {
  __builtin_amdgcn_global_load_lds((const __attribute__((address_space(1))) void*)g,
                                   (__attribute__((address_space(3))) void*)l, 16, 0, 0);
}

// ---------------------------------------------------------------------------
// 64x64 f32->bf16 transposing tile cast via LDS. dst[c][r] = src[r][c].
// Optional pass-through row-major bf16 write (thru).
// ---------------------------------------------------------------------------
template<int WRITE_THRU>
__device__ __forceinline__ void tcast64(const float* __restrict__ src, int sld,
                                        unsigned short* __restrict__ dst, int dld,
                                        unsigned short* __restrict__ thru, int tld, int t)
{
  __shared__ float L[64][65];
#pragma unroll
  for (int q = 0; q < 4; ++q) {
    const int fi = t + q * 256;          // 0..1023
    const int r = fi >> 4, c4 = fi & 15; // row, col-group of 4
    fv4 v = *(const fv4*)(src + (long)r * sld + c4 * 4);
    L[r][c4 * 4 + 0] = v.x; L[r][c4 * 4 + 1] = v.y;
    L[r][c4 * 4 + 2] = v.z; L[r][c4 * 4 + 3] = v.w;
    if (WRITE_THRU) {
      us4_t o; o.x = f2bf(v.x); o.y = f2bf(v.y); o.z = f2bf(v.z); o.w = f2bf(v.w);
      *(us4_t*)(thru + (long)r * tld + c4 * 4) = o;
    }
  }
  __syncthreads();
#pragma unroll
  for (int q = 0; q < 2; ++q) {
    const int wi = t + q * 256;          // 0..511
    const int rr = wi >> 3, ng = wi & 7; // dst row, 8-col group
    us8_t o;
#pragma unroll
    for (int j = 0; j < 8; ++j) o[j] = f2bf(L[ng * 8 + j][rr]);
    *(us8_t*)(dst + (long)rr * dld + ng * 8) = o;
  }
  __syncthreads();
}

// K1a: x -> xb (row-major bf16) AND xbT (transposed bf16 [b][d][n])
__global__ __launch_bounds__(256) void transpose_cast_x(
    const float* __restrict__ x, unsigned short* __restrict__ xb,
    unsigned short* __restrict__ xbT)
{
  const int nx = blockIdx.x, dx = blockIdx.y, b = blockIdx.z;
  const int n0 = nx * 64, d0 = dx * 64;
  const float* src = x + ((long)b * NN + n0) * DD + d0;
  unsigned short* thru = xb + ((long)b * NN + n0) * DD + d0;
  unsigned short* dst = xbT + ((long)b * DD + d0) * NN + n0;
  tcast64<1>(src, DD, dst, NN, thru, DD, threadIdx.x);
}

// K1b: W2=[wq;wk] bf16 [1536][768]; wvT bf16 [768(k)][768(i)] = wv^T; zeros
__global__ __launch_bounds__(256) void small_cast(
    const float* __restrict__ wq, const float* __restrict__ wk, const float* __restrict__ wv,
    unsigned short* __restrict__ W2, unsigned short* __restrict__ wvT,
    float* __restrict__ zeros)
{
  const int blk = blockIdx.x, t = threadIdx.x;
  if (blk < 576) {
    // 1536x768 = 1179648 elems = 576 blocks * 512 fv4-ish groups
#pragma unroll
    for (int q = 0; q < 2; ++q) {
      long g = (long)blk * 512 + t * 2 + q;   // fv4 index
      long e0 = g * 4;
      int row = (int)(e0 / DD), col = (int)(e0 % DD);
      const float* src = (row < DD) ? (wq + (long)row * DD + col)
                                    : (wk + (long)(row - DD) * DD + col);
      fv4 v = *(const fv4*)src;
      us4_t o; o.x = f2bf(v.x); o.y = f2bf(v.y); o.z = f2bf(v.z); o.w = f2bf(v.w);
      *(us4_t*)(W2 + e0) = o;
    }
  } else if (blk < 720) {
    const int tile = blk - 576;
    const int ti = tile / 12, tj = tile % 12;  // k-block, i-block
    const int k0 = ti * 64, i0 = tj * 64;
    // wvT[k][i] = wv[i][k]
    tcast64<0>(wv + (long)i0 * DD + k0, DD, wvT + (long)k0 * DD + i0, DD, nullptr, 0, t);
  } else {
#pragma unroll
    for (int q = 0; q < 4; ++q) zeros[t * 4 + q] = 0.f;
  }
}

// K1c: xsum[b][d] = sum_n x[b][n][d], read from xbT rows (contiguous).
__global__ __launch_bounds__(256) void colsum(
    const unsigned short* __restrict__ xbT, float* __restrict__ xsum)
{
  const int bx = blockIdx.x, b = blockIdx.y;
  const int wave = threadIdx.x >> 6, lane = threadIdx.x & 63;
  const int d = bx * 4 + wave;
  const unsigned short* row = xbT + ((long)b * DD + d) * NN;
  float s = 0.f;
#pragma unroll
  for (int it = 0; it < 8; ++it) {
    us8_t v = *(const us8_t*)(row + (it * 64 + lane) * 8);
#pragma unroll
    for (int j = 0; j < 8; ++j) s += bf2f(v[j]);
  }
#pragma unroll
  for (int off = 32; off > 0; off >>= 1) s += __shfl_down(s, off);
  if (lane == 0) xsum[(long)b * DD + d] = s;
}

// ---------------------------------------------------------------------------
// bf16 GEMM, C[m][n] = sum_k A[m][k] * Bt[n][k] + bias[n]  (per-z bias optional)
// 128x128 tile, BK=32, 4 waves (2x2 of 64x64), m97 structure.
// 1-D grid + XCD-chunked bijective swizzle (T1; all call sites have nwg%8==0):
//   wid = (bid&7)*(nwg/8) + bid/8, then wid -> (batch zb, tile t0), n-fastest.
// SYM=1 (A==Bt, square): only upper-triangle tiles (t0 -> i0<=j0); mirror
// tile written transposed via packed us4 (lane's 4 acc rows are consecutive
// -> 4 consecutive cols in the mirror). Halves the S-GEMM work (round-5: S
// was the top dispatch, 155us, FETCH 391MB from cross-batch L2 thrash).
// OUT_BF16=1 -> bf16 store, else f32 store.
// ---------------------------------------------------------------------------
template<int OUT_BF16, int SYM>
__global__ __launch_bounds__(256) void gemm_bt(
    const unsigned short* __restrict__ A, int lda, long aStride,
    const unsigned short* __restrict__ Bt, int ldb, long bStride,
    void* __restrict__ Cv, int ldc, long cStride,
    const float* __restrict__ bias, long biasStride, int K,
    int perB, int nt)
{
  __shared__ unsigned short As[128 * 32];
  __shared__ unsigned short Bs[128 * 32];
  const int nwg = gridDim.x;
  const int bid = blockIdx.x;
  const int wid = (bid & 7) * (nwg >> 3) + (bid >> 3);   // XCD-chunked
  const int zb = wid / perB;
  const int t0 = wid % perB;
  int i0, j0;
  if (SYM) {
    int tt = t0; i0 = 0;
    while (tt >= nt - i0) { tt -= nt - i0; ++i0; }
    j0 = i0 + tt;
  } else {
    i0 = t0 / nt; j0 = t0 % nt;   // n fastest: consecutive blocks share A-panel
  }
  const unsigned short* Ab = A + (long)zb * aStride;
  const unsigned short* Bb = Bt + (long)zb * bStride;
  const float* bz = bias + (long)zb * biasStride;
  const long m0 = (long)i0 * 128;
  const int n0 = j0 * 128;
  const int t = threadIdx.x;
  const int wave = t >> 6, lane = t & 63;
  const int wr = wave >> 1, wc = wave & 1;

  f32x4_t acc[4][4] = {};

  // staging geometry: byte offset o in 8KB tile; row = o>>6 (32 bf16 = 64B rows)
  const int o0 = t * 16;
  const int row0 = o0 >> 6, kc0 = (o0 & 63) >> 1;
  const int o1 = 4096 + t * 16;
  const int row1 = o1 >> 6, kc1 = (o1 & 63) >> 1;
  unsigned short* ldsA = As + wave * 512;  // + lane*16B by HW
  unsigned short* ldsB = Bs + wave * 512;

  for (int kt = 0; kt < K; kt += 32) {
    load_lds16(Ab + (m0 + row0) * (long)lda + kt + kc0, ldsA);
    load_lds16(Ab + (m0 + row1) * (long)lda + kt + kc1, ldsA + 2048);
    load_lds16(Bb + (long)(n0 + row0) * ldb + kt + kc0, ldsB);
    load_lds16(Bb + (long)(n0 + row1) * ldb + kt + kc1, ldsB + 2048);
    __syncthreads();
    bf16x8_t af[4], bfr[4];
    const int kofs = (lane >> 4) << 3;
#pragma unroll
    for (int f = 0; f < 4; ++f) {
      af[f]  = *(const bf16x8_t*)&As[(wr * 64 + f * 16 + (lane & 15)) * 32 + kofs];
      bfr[f] = *(const bf16x8_t*)&Bs[(wc * 64 + f * 16 + (lane & 15)) * 32 + kofs];
    }
#pragma unroll
    for (int i = 0; i < 4; ++i)
#pragma unroll
      for (int j = 0; j < 4; ++j)
        acc[i][j] = __builtin_amdgcn_mfma_f32_16x16x32_bf16(af[i], bfr[j], acc[i][j], 0, 0, 0);
    __syncthreads();
  }

  // epilogue: D col = lane&15, row = (lane>>4)*4 + r  (m89-verified layout)
  const int col_l = lane & 15;
  const int rbase = (lane >> 4) << 2;
#pragma unroll
  for (int i = 0; i < 4; ++i) {
    const long growb = m0 + wr * 64 + i * 16 + rbase;
#pragma unroll
    for (int j = 0; j < 4; ++j) {
      const int col = n0 + wc * 64 + j * 16 + col_l;
      if (OUT_BF16) {
        const float bcol = bz[col];
        us4_t o;
#pragma unroll
        for (int r = 0; r < 4; ++r) o[r] = f2bf(acc[i][j][r] + bcol);
        unsigned short* cb = (unsigned short*)Cv + (long)zb * cStride;
#pragma unroll
        for (int r = 0; r < 4; ++r) cb[(growb + r) * ldc + col] = o[r];
        if (SYM && i0 != j0)   // mirror tile, transposed, packed 8B store
          *(us4_t*)(cb + (long)col * ldc + growb) = o;
      } else {
#pragma unroll
        for (int r = 0; r < 4; ++r) {
          float* crow = (float*)Cv + (long)zb * cStride + (growb + r) * ldc;
          crow[col] = acc[i][j][r] + bz[col];
        }
      }
    }
  }
}

// ---------------------------------------------------------------------------
// K3a: per (b,h,kc): partial E_h = Tq_h * wk_h^T over k' in [kc*384,+384),
// plus diag(Tq_h*wq_h^T) -> nq2, diag(Tk_h*wk_h^T) -> nk2 (MFMA diag trick).
// Tq_h = T[b] rows [h*48,+48), Tk_h = rows [768+h*48,+48); same for W2.
// Staged via global_load_lds with the round-4-proven 16B-block XOR swizzle
// (pre-swizzled global source + swizzled frag reads; rows 256B).
// Writes fp32 partials Gp[((b*H+h)*2+kc)][2464]:
//   [0..2352) = E (48 rows x stride 49), [2352..2400) nq2, [2400..2448) nk2.
// ---------------------------------------------------------------------------
#define GP_STRIDE 2464

__global__ __launch_bounds__(256) void energy_partial2(
    const unsigned short* __restrict__ T, const unsigned short* __restrict__ W2,
    float* __restrict__ Gp)
{
  __shared__ unsigned short Ts[2][48 * 128];   // Tq, Tk tiles (12KB each)
  __shared__ unsigned short Ws[2][48 * 128];   // wq, wk tiles
  __shared__ float G_sh[2448];

  const int kc = blockIdx.x, h = blockIdx.y, b = blockIdx.z;
  const int t = threadIdx.x;
  const int wave = t >> 6, lane = t & 63;

  for (int i = t; i < 2448; i += 256) G_sh[i] = 0.f;

  f32x4_t accG[3][3] = {};
  f32x4_t accQ[3] = {};
  f32x4_t accK[3] = {};

  // staging source offsets: linear LDS byte L = p*4096 + wave*1024 + lane*16
  // -> e = L>>8, 16B-block blk = (L>>4)&15; inverse-swizzled source k-block
  long qoff[3];
#pragma unroll
  for (int p = 0; p < 3; ++p) {
    const int L = p * 4096 + wave * 1024 + lane * 16;
    const int e = L >> 8;
    const int blk = (L >> 4) & 15;
    const int sblk = blk ^ (e & 7);
    qoff[p] = (long)e * DD + sblk * 8;
  }
  const unsigned short* Tq = T + ((long)b * 1536 + h * 48) * DD;
  const unsigned short* Tk = Tq + (long)DD * DD;
  const unsigned short* Wq = W2 + (long)h * 48 * DD;
  const unsigned short* Wk = Wq + (long)DD * DD;

  // frag read offsets (bytes, swizzled): e = f*16+(lane&15), k-blk = wave*4+(lane>>4)
  int foff[3];
#pragma unroll
  for (int f = 0; f < 3; ++f) {
    const int e = f * 16 + (lane & 15);
    foff[f] = e * 256 + (((wave * 4 + (lane >> 4)) ^ (e & 7)) << 4);
  }
  __syncthreads();

  for (int ci = 0; ci < 3; ++ci) {
    const int col0 = kc * 384 + ci * 128;
#pragma unroll
    for (int p = 0; p < 3; ++p) {
      load_lds16(Tq + qoff[p] + col0, &Ts[0][p * 2048] + wave * 512);
      load_lds16(Tk + qoff[p] + col0, &Ts[1][p * 2048] + wave * 512);
      load_lds16(Wq + qoff[p] + col0, &Ws[0][p * 2048] + wave * 512);
      load_lds16(Wk + qoff[p] + col0, &Ws[1][p * 2048] + wave * 512);
    }
    __syncthreads();
    bf16x8_t tq[3], tk[3], wqf[3], wkf[3];
#pragma unroll
    for (int f = 0; f < 3; ++f) {
      tq[f]  = *(const bf16x8_t*)((const char*)&Ts[0][0] + foff[f]);
      tk[f]  = *(const bf16x8_t*)((const char*)&Ts[1][0] + foff[f]);
      wqf[f] = *(const bf16x8_t*)((const char*)&Ws[0][0] + foff[f]);
      wkf[f] = *(const bf16x8_t*)((const char*)&Ws[1][0] + foff[f]);
    }
#pragma unroll
    for (int i = 0; i < 3; ++i) {
      accQ[i] = __builtin_amdgcn_mfma_f32_16x16x32_bf16(tq[i], wqf[i], accQ[i], 0, 0, 0);
      accK[i] = __builtin_amdgcn_mfma_f32_16x16x32_bf16(tk[i], wkf[i], accK[i], 0, 0, 0);
#pragma unroll
      for (int j = 0; j < 3; ++j)
        accG[i][j] = __builtin_amdgcn_mfma_f32_16x16x32_bf16(tq[i], wkf[j], accG[i][j], 0, 0, 0);
    }
    __syncthreads();
  }

  // cross-wave reduce into LDS
#pragma unroll
  for (int i = 0; i < 3; ++i)
#pragma unroll
    for (int j = 0; j < 3; ++j) {
      int e = i * 16 + ((lane >> 4) << 2);
      int qi = j * 16 + (lane & 15);
#pragma unroll
      for (int r = 0; r < 4; ++r) atomicAdd(&G_sh[(e + r) * 49 + qi], accG[i][j][r]);
    }
  // diagonal lanes contribute the norms
  if ((lane >> 4) == ((lane & 15) >> 2)) {
    int r = (lane & 15) & 3;
#pragma unroll
    for (int f = 0; f < 3; ++f) {
      atomicAdd(&G_sh[2352 + f * 16 + (lane & 15)], accQ[f][r]);
      atomicAdd(&G_sh[2400 + f * 16 + (lane & 15)], accK[f][r]);
    }
  }
  __syncthreads();

  float* out = Gp + (long)(((b * HH + h) << 1) + kc) * GP_STRIDE;
  for (int i = t; i < 2448; i += 256) out[i] = G_sh[i];
}

// ---------------------------------------------------------------------------
// K3b: per (b,h): reduce 2 partials, apply bias corrections (exact-zero-cost
// when bq=bk=0: runtime check skips them), norms, softmax, /tau.
// Writes A bf16 padded [48][64] (cols 48..63 zero) for build_btf.
// ---------------------------------------------------------------------------
__global__ __launch_bounds__(256) void energy_finish2(
    const float* __restrict__ Gp, const float* __restrict__ xsum,
    const float* __restrict__ wq, const float* __restrict__ wk,
    const float* __restrict__ bq, const float* __restrict__ bk,
    const float* __restrict__ tau_p, unsigned short* __restrict__ A_out)
{
  __shared__ float G_sh[2448];
  __shared__ float vq[48], vk[48], bqs[48], bks[48];
  __shared__ int has_bias;
  const int h = blockIdx.x, b = blockIdx.y;
  const int t = threadIdx.x;

  const float* base = Gp + (long)((b * HH + h) << 1) * GP_STRIDE;
  for (int i = t; i < 2448; i += 256)
    G_sh[i] = base[i] + base[GP_STRIDE + i];
  if (t < 48) { bqs[t] = bq[h * 48 + t]; bks[t] = bk[h * 48 + t]; }
  __syncthreads();
  if (t == 0) {
    float s = 0.f;
    for (int i = 0; i < 48; ++i) s += fabsf(bqs[i]) + fabsf(bks[i]);
    has_bias = (s != 0.f);
  }
  __syncthreads();
  if (has_bias) {
    // vq[e] = wq_h[e,:] . xsum[b],  vk[q] = wk_h[q,:] . xsum[b]
    if (t < 96) {
      const int e = t < 48 ? t : t - 48;
      const float* wrow = (t < 48 ? wq : wk) + (long)(h * 48 + e) * DD;
      const float* xs = xsum + (long)b * DD;
      float s = 0.f;
      for (int g = 0; g < DD / 4; ++g) {
        fv4 a = *(const fv4*)(wrow + g * 4);
        fv4 c = *(const fv4*)(xs + g * 4);
        s += a.x * c.x + a.y * c.y + a.z * c.z + a.w * c.w;
      }
      if (t < 48) vq[e] = s; else vk[e] = s;
    }
  } else if (t < 48) { vq[t] = 0.f; vk[t] = 0.f; }
  __syncthreads();

  if (t < 48) {
    const float tau = *tau_p;
    const float nq2c = G_sh[2352 + t] + 2.f * bqs[t] * vq[t] + (float)NN * bqs[t] * bqs[t];
    const float nq = fmaxf(sqrtf(nq2c), 1e-12f);
    float row[48];
    float mx = -1e30f;
#pragma unroll 1
    for (int qi = 0; qi < 48; ++qi) {
      float nk2c = G_sh[2400 + qi] + 2.f * bks[qi] * vk[qi] + (float)NN * bks[qi] * bks[qi];
      float nk = fmaxf(sqrtf(nk2c), 1e-12f);
      float e = G_sh[t * 49 + qi] + vq[t] * bks[qi] + bqs[t] * vk[qi]
              + (float)NN * bqs[t] * bks[qi];
      float g = e / (nq * nk);
      row[qi] = g; mx = fmaxf(mx, g);
    }
    float s = 0.f;
#pragma unroll 1
    for (int qi = 0; qi < 48; ++qi) { row[qi] = __expf(row[qi] - mx); s += row[qi]; }
    const float inv = 1.f / (s * tau);
    unsigned short* dst = A_out + (((long)b * HH + h) * 48) * 64 + (long)t * 64;
#pragma unroll 1
    for (int qi = 0; qi < 48; ++qi) dst[qi] = f2bf(row[qi] * inv);
#pragma unroll 1
    for (int qi = 48; qi < 64; ++qi) dst[qi] = 0;
  }
}

// ---------------------------------------------------------------------------
// K4: Btf[b][no][h*48+e] = sum_qi A_h[e][qi] * wo[no][h*48+qi]   (MFMA, K=48
// padded to 64). A-operand = wo rows (qi-contiguous), B-operand = A_h rows.
// ---------------------------------------------------------------------------
__global__ __launch_bounds__(256) void build_btf(
    const unsigned short* __restrict__ A_ws, const float* __restrict__ wo,
    unsigned short* __restrict__ btf)
{
  __shared__ unsigned short Wsh[128 * 72];
  __shared__ unsigned short Ash[48 * 72];
  const int nchunk = blockIdx.x, h = blockIdx.y, b = blockIdx.z;
  const int t = threadIdx.x;
  const int wave = t >> 6, lane = t & 63;
  const int no0 = nchunk * 128;

  for (int i = t; i < 128 * 64; i += 256) {
    int r = i >> 6, c = i & 63;
    Wsh[r * 72 + c] = (c < 48) ? f2bf(wo[(long)(no0 + r) * DD + h * 48 + c]) : (unsigned short)0;
  }
  const unsigned short* Asrc = A_ws + ((long)b * HH + h) * 48 * 64;
  for (int i = t; i < 48 * 64; i += 256) {
    int r = i >> 6, c = i & 63;
    Ash[r * 72 + c] = Asrc[r * 64 + c];   // already zero-padded in cols 48..63
  }
  __syncthreads();

  f32x4_t acc[2][3] = {};
#pragma unroll
  for (int ks = 0; ks < 2; ++ks) {
    const int k0 = ks * 32 + ((lane >> 4) << 3);
    bf16x8_t af[2], bfr[3];
#pragma unroll
    for (int mi = 0; mi < 2; ++mi)
      af[mi] = *(const bf16x8_t*)&Wsh[(wave * 32 + mi * 16 + (lane & 15)) * 72 + k0];
#pragma unroll
    for (int nj = 0; nj < 3; ++nj)
      bfr[nj] = *(const bf16x8_t*)&Ash[(nj * 16 + (lane & 15)) * 72 + k0];
#pragma unroll
    for (int mi = 0; mi < 2; ++mi)
#pragma unroll
      for (int nj = 0; nj < 3; ++nj)
        acc[mi][nj] = __builtin_amdgcn_mfma_f32_16x16x32_bf16(af[mi], bfr[nj], acc[mi][nj], 0, 0, 0);
  }

  const int col_l = lane & 15;
  const int rbase = (lane >> 4) << 2;
#pragma unroll
  for (int mi = 0; mi < 2; ++mi)
#pragma unroll
    for (int r = 0; r < 4; ++r) {
      int no = no0 + wave * 32 + mi * 16 + rbase + r;
      unsigned short* dst = btf + ((long)b * DD + no) * DD + h * 48;
#pragma unroll
      for (int nj = 0; nj < 3; ++nj)
        dst[nj * 16 + col_l] = f2bf(acc[mi][nj][r]);
    }
}

// ---------------------------------------------------------------------------
// K5: bias2[b][j] = bo[j] + sum_i bv[i]*Btf[b][j][i]
// ---------------------------------------------------------------------------
__global__ __launch_bounds__(256) void build_bias2(
    const unsigned short* __restrict__ btf, const float* __restrict__ bv,
    const float* __restrict__ bo, float* __restrict__ bias2)
{
  const int bx = blockIdx.x, b = blockIdx.y;
  const int wave = threadIdx.x >> 6, lane = threadIdx.x & 63;
  const int j = bx * 4 + wave;
  const unsigned short* row = btf + ((long)b * DD + j) * DD;
  float s = 0.f;
#pragma unroll
  for (int ii = 0; ii < 12; ++ii) {
    int i = ii * 64 + lane;
    s += bf2f(row[i]) * bv[i];
  }
#pragma unroll
  for (int off = 32; off > 0; off >>= 1) s += __shfl_down(s, off);
  if (lane == 0) bias2[(long)b * DD + j] = bo[j] + s;
}

// ---------------------------------------------------------------------------
extern "C" void kernel_launch(void* const* d_in, const int* in_sizes, int n_in,
                              void* d_out, int out_size, void* d_ws, size_t ws_size,
                              hipStream_t stream)
{
  (void)in_sizes; (void)n_in; (void)out_size;
  const float* x   = (const float*)d_in[0];
  const float* wq  = (const float*)d_in[1];
  const float* bq  = (const float*)d_in[2];
  const float* wk  = (const float*)d_in[3];
  const float* bk  = (const float*)d_in[4];
  const float* wv  = (const float*)d_in[5];
  const float* bv  = (const float*)d_in[6];
  const float* wo  = (const float*)d_in[7];
  const float* bo  = (const float*)d_in[8];
  const float* tau = (const float*)d_in[9];

  char* ws = (char*)d_ws;
  // layout (bytes) — no aliasing needed (306 MB total < proven ws >= 425 MB)
  unsigned short* xb    = (unsigned short*)(ws + 0L);          // 100663296
  unsigned short* xbT   = (unsigned short*)(ws + 100663296L);  // 100663296
  unsigned short* S     = (unsigned short*)(ws + 201326592L);  // 16*768*768*2 = 18874368
  unsigned short* T     = (unsigned short*)(ws + 220200960L);  // 16*1536*768*2 = 37748736
  unsigned short* W2    = (unsigned short*)(ws + 257949696L);  // 2359296
  unsigned short* wvT   = (unsigned short*)(ws + 260308992L);  // 1179648
  float*          zeros = (float*)         (ws + 261488640L);  // 4096
  float*          xsum  = (float*)         (ws + 261492736L);  // 49152
  float*          Gp    = (float*)         (ws + 261541888L);  // 512*2464*4 = 5046272
  unsigned short* A_ws  = (unsigned short*)(ws + 266588160L);  // 1572864
  unsigned short* btf   = (unsigned short*)(ws + 268161024L);  // 18874368
  unsigned short* Ctf   = (unsigned short*)(ws + 287035392L);  // 18874368
  float*          bias2 = (float*)         (ws + 305909760L);  // 49152 -> ends 305958912
  if (ws_size < 305958912ULL) return;

  transpose_cast_x<<<dim3(64, 12, BB), 256, 0, stream>>>(x, xb, xbT);
  small_cast<<<721, 256, 0, stream>>>(wq, wk, wv, W2, wvT, zeros);
  colsum<<<dim3(192, BB), 256, 0, stream>>>(xbT, xsum);

  // S[b] = x[b]^T x[b]  (768x768 symmetric, K=4096): 21 triangle tiles/batch
  gemm_bt<1, 1><<<16 * 21, 256, 0, stream>>>(
      xbT, NN, (long)DD * NN, xbT, NN, (long)DD * NN,
      S, DD, (long)DD * DD, zeros, 0L, NN, 21, 6);

  // T[b] = W2 * S[b]  (1536x768, K=768; S symmetric -> Bt=S), bf16 out
  gemm_bt<1, 0><<<16 * 72, 256, 0, stream>>>(
      W2, DD, 0L, S, DD, (long)DD * DD,
      T, DD, (long)1536 * DD, zeros, 0L, DD, 72, 6);

  energy_partial2<<<dim3(2, HH, BB), 256, 0, stream>>>(T, W2, Gp);
  energy_finish2<<<dim3(HH, BB), 256, 0, stream>>>(Gp, xsum, wq, wk, bq, bk, tau, A_ws);

  build_btf<<<dim3(6, HH, BB), 256, 0, stream>>>(A_ws, wo, btf);
  build_bias2<<<dim3(192, BB), 256, 0, stream>>>(btf, bv, bo, bias2);

  // Ctf[b] = Btf[b] * wv  (768x768, K=768), bf16 out
  gemm_bt<1, 0><<<16 * 36, 256, 0, stream>>>(
      btf, DD, (long)DD * DD, wvT, DD, 0L,
      Ctf, DD, (long)DD * DD, zeros, 0L, DD, 36, 6);

  // out[b] = x[b] * Ctf[b]^T + bias2[b]  (4096x768, K=768), f32 out
  gemm_bt<0, 0><<<16 * 192, 256, 0, stream>>>(
      xb, DD, (long)NN * DD, Ctf, DD, (long)DD * DD,
      d_out, DD, (long)NN * DD, bias2, (long)DD, DD, 192, 6);
}

// Round 7
// 484.193 us; speedup vs baseline: 2.5079x; 1.0526x over previous
//
#include <hip/hip_runtime.h>
#include <hip/hip_bf16.h>

typedef __attribute__((ext_vector_type(8))) short bf16x8_t;   // MFMA A/B frag (8 bf16)
typedef __attribute__((ext_vector_type(4))) float f32x4_t;    // MFMA C/D frag
typedef __attribute__((ext_vector_type(4))) float fv4;
typedef __attribute__((ext_vector_type(4))) unsigned short us4_t;
typedef __attribute__((ext_vector_type(8))) unsigned short us8_t;

// Problem constants
static constexpr int BB = 16, NN = 4096, DD = 768, HH = 16, EE = 48;

__device__ __forceinline__ unsigned short f2bf(float f) {
  unsigned int u = __float_as_uint(f);
  u += 0x7fffu + ((u >> 16) & 1u);   // RNE; inputs are finite
  return (unsigned short)(u >> 16);
}
__device__ __forceinline__ float bf2f(unsigned short s) {
  unsigned int u = ((unsigned int)s) << 16;
  return __uint_as_float(u);
}

__device__ __forceinline__ void load_lds16(const void* g, void* l) {
  __builtin_amdgcn_global_load_lds((const __attribute__((address_space(1))) void*)g,
                                   (__attribute__((address_space(3))) void*)l, 16, 0, 0);
}

// ---------------------------------------------------------------------------
// 64x64 f32->bf16 transposing tile cast via LDS. dst[c][r] = src[r][c].
// Optional pass-through row-major bf16 write (thru).
// ---------------------------------------------------------------------------
template<int WRITE_THRU>
__device__ __forceinline__ void tcast64(const float* __restrict__ src, int sld,
                                        unsigned short* __restrict__ dst, int dld,
                                        unsigned short* __restrict__ thru, int tld, int t)
{
  __shared__ float L[64][65];
#pragma unroll
  for (int q = 0; q < 4; ++q) {
    const int fi = t + q * 256;          // 0..1023
    const int r = fi >> 4, c4 = fi & 15; // row, col-group of 4
    fv4 v = *(const fv4*)(src + (long)r * sld + c4 * 4);
    L[r][c4 * 4 + 0] = v.x; L[r][c4 * 4 + 1] = v.y;
    L[r][c4 * 4 + 2] = v.z; L[r][c4 * 4 + 3] = v.w;
    if (WRITE_THRU) {
      us4_t o; o.x = f2bf(v.x); o.y = f2bf(v.y); o.z = f2bf(v.z); o.w = f2bf(v.w);
      *(us4_t*)(thru + (long)r * tld + c4 * 4) = o;
    }
  }
  __syncthreads();
#pragma unroll
  for (int q = 0; q < 2; ++q) {
    const int wi = t + q * 256;          // 0..511
    const int rr = wi >> 3, ng = wi & 7; // dst row, 8-col group
    us8_t o;
#pragma unroll
    for (int j = 0; j < 8; ++j) o[j] = f2bf(L[ng * 8 + j][rr]);
    *(us8_t*)(dst + (long)rr * dld + ng * 8) = o;
  }
  __syncthreads();
}

// K1a: x -> xb (row-major bf16) AND xbT (transposed bf16 [b][d][n])
__global__ __launch_bounds__(256) void transpose_cast_x(
    const float* __restrict__ x, unsigned short* __restrict__ xb,
    unsigned short* __restrict__ xbT)
{
  const int nx = blockIdx.x, dx = blockIdx.y, b = blockIdx.z;
  const int n0 = nx * 64, d0 = dx * 64;
  const float* src = x + ((long)b * NN + n0) * DD + d0;
  unsigned short* thru = xb + ((long)b * NN + n0) * DD + d0;
  unsigned short* dst = xbT + ((long)b * DD + d0) * NN + n0;
  tcast64<1>(src, DD, dst, NN, thru, DD, threadIdx.x);
}

// K1b: W2=[wq;wk] bf16 [1536][768]; wvT bf16 [768(k)][768(i)] = wv^T; zeros
__global__ __launch_bounds__(256) void small_cast(
    const float* __restrict__ wq, const float* __restrict__ wk, const float* __restrict__ wv,
    unsigned short* __restrict__ W2, unsigned short* __restrict__ wvT,
    float* __restrict__ zeros)
{
  const int blk = blockIdx.x, t = threadIdx.x;
  if (blk < 576) {
    // 1536x768 = 1179648 elems = 576 blocks * 512 fv4-ish groups
#pragma unroll
    for (int q = 0; q < 2; ++q) {
      long g = (long)blk * 512 + t * 2 + q;   // fv4 index
      long e0 = g * 4;
      int row = (int)(e0 / DD), col = (int)(e0 % DD);
      const float* src = (row < DD) ? (wq + (long)row * DD + col)
                                    : (wk + (long)(row - DD) * DD + col);
      fv4 v = *(const fv4*)src;
      us4_t o; o.x = f2bf(v.x); o.y = f2bf(v.y); o.z = f2bf(v.z); o.w = f2bf(v.w);
      *(us4_t*)(W2 + e0) = o;
    }
  } else if (blk < 720) {
    const int tile = blk - 576;
    const int ti = tile / 12, tj = tile % 12;  // k-block, i-block
    const int k0 = ti * 64, i0 = tj * 64;
    // wvT[k][i] = wv[i][k]
    tcast64<0>(wv + (long)i0 * DD + k0, DD, wvT + (long)k0 * DD + i0, DD, nullptr, 0, t);
  } else {
#pragma unroll
    for (int q = 0; q < 4; ++q) zeros[t * 4 + q] = 0.f;
  }
}

// K1c: xsum[b][d] = sum_n x[b][n][d], read from xbT rows (contiguous).
__global__ __launch_bounds__(256) void colsum(
    const unsigned short* __restrict__ xbT, float* __restrict__ xsum)
{
  const int bx = blockIdx.x, b = blockIdx.y;
  const int wave = threadIdx.x >> 6, lane = threadIdx.x & 63;
  const int d = bx * 4 + wave;
  const unsigned short* row = xbT + ((long)b * DD + d) * NN;
  float s = 0.f;
#pragma unroll
  for (int it = 0; it < 8; ++it) {
    us8_t v = *(const us8_t*)(row + (it * 64 + lane) * 8);
#pragma unroll
    for (int j = 0; j < 8; ++j) s += bf2f(v[j]);
  }
#pragma unroll
  for (int off = 32; off > 0; off >>= 1) s += __shfl_down(s, off);
  if (lane == 0) xsum[(long)b * DD + d] = s;
}

// ---------------------------------------------------------------------------
// bf16 GEMM, C[m][n] = sum_k A[m][k] * Bt[n][k] + bias[n]  (per-z bias optional)
// 128x128 tile, BK=64, 4 waves (2x2 of 64x64).
// Round-6 upgrade: BK=32 had 64B LDS rows -> ds_read_b128 8-way bank conflict
// (9.4M/dispatch) and 2 barriers per 32 K-elems. BK=64 gives 128B rows:
//  - full XOR swizzle blk^=(row&7) -> bank group depends only on block -> free
//    (both-sides-or-neither, rule #21: inverse-swizzled GLOBAL source for
//    global_load_lds (linear dest) + swizzled frag ds_read; proven pattern
//    from energy_partial2)
//  - barriers per K-elem halved. LDS 32KB -> ~4 blocks/CU.
// 1-D grid + XCD-chunked bijective swizzle (T1; all call sites nwg%8==0).
// SYM=1 (A==Bt, square): upper-triangle tiles only; mirror tile written
// transposed via packed us4. OUT_BF16=1 -> bf16 store, else f32 store.
// ---------------------------------------------------------------------------
template<int OUT_BF16, int SYM>
__global__ __launch_bounds__(256) void gemm_bt(
    const unsigned short* __restrict__ A, int lda, long aStride,
    const unsigned short* __restrict__ Bt, int ldb, long bStride,
    void* __restrict__ Cv, int ldc, long cStride,
    const float* __restrict__ bias, long biasStride, int K,
    int perB, int nt)
{
  __shared__ unsigned short As[128 * 64];
  __shared__ unsigned short Bs[128 * 64];
  const int nwg = gridDim.x;
  const int bid = blockIdx.x;
  const int wid = (bid & 7) * (nwg >> 3) + (bid >> 3);   // XCD-chunked
  const int zb = wid / perB;
  const int t0 = wid % perB;
  int i0, j0;
  if (SYM) {
    int tt = t0; i0 = 0;
    while (tt >= nt - i0) { tt -= nt - i0; ++i0; }
    j0 = i0 + tt;
  } else {
    i0 = t0 / nt; j0 = t0 % nt;   // n fastest: consecutive blocks share A-panel
  }
  const unsigned short* Ab = A + (long)zb * aStride;
  const unsigned short* Bb = Bt + (long)zb * bStride;
  const float* bz = bias + (long)zb * biasStride;
  const long m0 = (long)i0 * 128;
  const int n0 = j0 * 128;
  const int t = threadIdx.x;
  const int wave = t >> 6, lane = t & 63;
  const int wr = wave >> 1, wc = wave & 1;

  f32x4_t acc[4][4] = {};

  // staging: thread t covers LDS bytes p*4096 + t*16 (p=0..3, linear dest).
  // row = p*32 + (t>>3); block c = t&7; source block = c ^ (row&7).
  const int srow = t >> 3;                       // 0..31
  const long scol = (long)(((t & 7) ^ (srow & 7)) << 3);  // elems
  unsigned short* ldsA = As + wave * 512;        // +p*2048 per issue
  unsigned short* ldsB = Bs + wave * 512;

  for (int kt = 0; kt < K; kt += 64) {
#pragma unroll
    for (int p = 0; p < 4; ++p) {
      load_lds16(Ab + (m0 + p * 32 + srow) * (long)lda + kt + scol, ldsA + p * 2048);
      load_lds16(Bb + (long)(n0 + p * 32 + srow) * ldb + kt + scol, ldsB + p * 2048);
    }
    __syncthreads();
#pragma unroll
    for (int kk = 0; kk < 2; ++kk) {
      // frag read (swizzled): row = W*64+f*16+(lane&15); logical blk = kk*4+(lane>>4)
      const int cswz = (((kk << 2) + (lane >> 4)) ^ (lane & 7)) << 4;   // bytes
      bf16x8_t af[4], bfr[4];
#pragma unroll
      for (int f = 0; f < 4; ++f) {
        af[f]  = *(const bf16x8_t*)((const char*)As + (wr * 64 + f * 16 + (lane & 15)) * 128 + cswz);
        bfr[f] = *(const bf16x8_t*)((const char*)Bs + (wc * 64 + f * 16 + (lane & 15)) * 128 + cswz);
      }
#pragma unroll
      for (int i = 0; i < 4; ++i)
#pragma unroll
        for (int j = 0; j < 4; ++j)
          acc[i][j] = __builtin_amdgcn_mfma_f32_16x16x32_bf16(af[i], bfr[j], acc[i][j], 0, 0, 0);
    }
    __syncthreads();
  }

  // epilogue: D col = lane&15, row = (lane>>4)*4 + r  (m89-verified layout)
  const int col_l = lane & 15;
  const int rbase = (lane >> 4) << 2;
#pragma unroll
  for (int i = 0; i < 4; ++i) {
    const long growb = m0 + wr * 64 + i * 16 + rbase;
#pragma unroll
    for (int j = 0; j < 4; ++j) {
      const int col = n0 + wc * 64 + j * 16 + col_l;
      if (OUT_BF16) {
        const float bcol = bz[col];
        us4_t o;
#pragma unroll
        for (int r = 0; r < 4; ++r) o[r] = f2bf(acc[i][j][r] + bcol);
        unsigned short* cb = (unsigned short*)Cv + (long)zb * cStride;
#pragma unroll
        for (int r = 0; r < 4; ++r) cb[(growb + r) * ldc + col] = o[r];
        if (SYM && i0 != j0)   // mirror tile, transposed, packed 8B store
          *(us4_t*)(cb + (long)col * ldc + growb) = o;
      } else {
#pragma unroll
        for (int r = 0; r < 4; ++r) {
          float* crow = (float*)Cv + (long)zb * cStride + (growb + r) * ldc;
          crow[col] = acc[i][j][r] + bz[col];
        }
      }
    }
  }
}

// ---------------------------------------------------------------------------
// K3a: per (b,h,kc): partial E_h = Tq_h * wk_h^T over k' in [kc*384,+384),
// plus diag(Tq_h*wq_h^T) -> nq2, diag(Tk_h*wk_h^T) -> nk2 (MFMA diag trick).
// Tq_h = T[b] rows [h*48,+48), Tk_h = rows [768+h*48,+48); same for W2.
// Staged via global_load_lds with the round-4-proven 16B-block XOR swizzle
// (pre-swizzled global source + swizzled frag reads; rows 256B).
// Writes fp32 partials Gp[((b*H+h)*2+kc)][2464]:
//   [0..2352) = E (48 rows x stride 49), [2352..2400) nq2, [2400..2448) nk2.
// ---------------------------------------------------------------------------
#define GP_STRIDE 2464

__global__ __launch_bounds__(256) void energy_partial2(
    const unsigned short* __restrict__ T, const unsigned short* __restrict__ W2,
    float* __restrict__ Gp)
{
  __shared__ unsigned short Ts[2][48 * 128];   // Tq, Tk tiles (12KB each)
  __shared__ unsigned short Ws[2][48 * 128];   // wq, wk tiles
  __shared__ float G_sh[2448];

  const int kc = blockIdx.x, h = blockIdx.y, b = blockIdx.z;
  const int t = threadIdx.x;
  const int wave = t >> 6, lane = t & 63;

  for (int i = t; i < 2448; i += 256) G_sh[i] = 0.f;

  f32x4_t accG[3][3] = {};
  f32x4_t accQ[3] = {};
  f32x4_t accK[3] = {};

  // staging source offsets: linear LDS byte L = p*4096 + wave*1024 + lane*16
  // -> e = L>>8, 16B-block blk = (L>>4)&15; inverse-swizzled source k-block
  long qoff[3];
#pragma unroll
  for (int p = 0; p < 3; ++p) {
    const int L = p * 4096 + wave * 1024 + lane * 16;
    const int e = L >> 8;
    const int blk = (L >> 4) & 15;
    const int sblk = blk ^ (e & 7);
    qoff[p] = (long)e * DD + sblk * 8;
  }
  const unsigned short* Tq = T + ((long)b * 1536 + h * 48) * DD;
  const unsigned short* Tk = Tq + (long)DD * DD;
  const unsigned short* Wq = W2 + (long)h * 48 * DD;
  const unsigned short* Wk = Wq + (long)DD * DD;

  // frag read offsets (bytes, swizzled): e = f*16+(lane&15), k-blk = wave*4+(lane>>4)
  int foff[3];
#pragma unroll
  for (int f = 0; f < 3; ++f) {
    const int e = f * 16 + (lane & 15);
    foff[f] = e * 256 + (((wave * 4 + (lane >> 4)) ^ (e & 7)) << 4);
  }
  __syncthreads();

  for (int ci = 0; ci < 3; ++ci) {
    const int col0 = kc * 384 + ci * 128;
#pragma unroll
    for (int p = 0; p < 3; ++p) {
      load_lds16(Tq + qoff[p] + col0, &Ts[0][p * 2048] + wave * 512);
      load_lds16(Tk + qoff[p] + col0, &Ts[1][p * 2048] + wave * 512);
      load_lds16(Wq + qoff[p] + col0, &Ws[0][p * 2048] + wave * 512);
      load_lds16(Wk + qoff[p] + col0, &Ws[1][p * 2048] + wave * 512);
    }
    __syncthreads();
    bf16x8_t tq[3], tk[3], wqf[3], wkf[3];
#pragma unroll
    for (int f = 0; f < 3; ++f) {
      tq[f]  = *(const bf16x8_t*)((const char*)&Ts[0][0] + foff[f]);
      tk[f]  = *(const bf16x8_t*)((const char*)&Ts[1][0] + foff[f]);
      wqf[f] = *(const bf16x8_t*)((const char*)&Ws[0][0] + foff[f]);
      wkf[f] = *(const bf16x8_t*)((const char*)&Ws[1][0] + foff[f]);
    }
#pragma unroll
    for (int i = 0; i < 3; ++i) {
      accQ[i] = __builtin_amdgcn_mfma_f32_16x16x32_bf16(tq[i], wqf[i], accQ[i], 0, 0, 0);
      accK[i] = __builtin_amdgcn_mfma_f32_16x16x32_bf16(tk[i], wkf[i], accK[i], 0, 0, 0);
#pragma unroll
      for (int j = 0; j < 3; ++j)
        accG[i][j] = __builtin_amdgcn_mfma_f32_16x16x32_bf16(tq[i], wkf[j], accG[i][j], 0, 0, 0);
    }
    __syncthreads();
  }

  // cross-wave reduce into LDS
#pragma unroll
  for (int i = 0; i < 3; ++i)
#pragma unroll
    for (int j = 0; j < 3; ++j) {
      int e = i * 16 + ((lane >> 4) << 2);
      int qi = j * 16 + (lane & 15);
#pragma unroll
      for (int r = 0; r < 4; ++r) atomicAdd(&G_sh[(e + r) * 49 + qi], accG[i][j][r]);
    }
  // diagonal lanes contribute the norms
  if ((lane >> 4) == ((lane & 15) >> 2)) {
    int r = (lane & 15) & 3;
#pragma unroll
    for (int f = 0; f < 3; ++f) {
      atomicAdd(&G_sh[2352 + f * 16 + (lane & 15)], accQ[f][r]);
      atomicAdd(&G_sh[2400 + f * 16 + (lane & 15)], accK[f][r]);
    }
  }
  __syncthreads();

  float* out = Gp + (long)(((b * HH + h) << 1) + kc) * GP_STRIDE;
  for (int i = t; i < 2448; i += 256) out[i] = G_sh[i];
}

// ---------------------------------------------------------------------------
// K3b: per (b,h): reduce 2 partials, apply bias corrections (exact-zero-cost
// when bq=bk=0: runtime check skips them), norms, softmax, /tau.
// Writes A bf16 padded [48][64] (cols 48..63 zero) for build_btf.
// ---------------------------------------------------------------------------
__global__ __launch_bounds__(256) void energy_finish2(
    const float* __restrict__ Gp, const float* __restrict__ xsum,
    const float* __restrict__ wq, const float* __restrict__ wk,
    const float* __restrict__ bq, const float* __restrict__ bk,
    const float* __restrict__ tau_p, unsigned short* __restrict__ A_out)
{
  __shared__ float G_sh[2448];
  __shared__ float vq[48], vk[48], bqs[48], bks[48];
  __shared__ int has_bias;
  const int h = blockIdx.x, b = blockIdx.y;
  const int t = threadIdx.x;

  const float* base = Gp + (long)((b * HH + h) << 1) * GP_STRIDE;
  for (int i = t; i < 2448; i += 256)
    G_sh[i] = base[i] + base[GP_STRIDE + i];
  if (t < 48) { bqs[t] = bq[h * 48 + t]; bks[t] = bk[h * 48 + t]; }
  __syncthreads();
  if (t == 0) {
    float s = 0.f;
    for (int i = 0; i < 48; ++i) s += fabsf(bqs[i]) + fabsf(bks[i]);
    has_bias = (s != 0.f);
  }
  __syncthreads();
  if (has_bias) {
    // vq[e] = wq_h[e,:] . xsum[b],  vk[q] = wk_h[q,:] . xsum[b]
    if (t < 96) {
      const int e = t < 48 ? t : t - 48;
      const float* wrow = (t < 48 ? wq : wk) + (long)(h * 48 + e) * DD;
      const float* xs = xsum + (long)b * DD;
      float s = 0.f;
      for (int g = 0; g < DD / 4; ++g) {
        fv4 a = *(const fv4*)(wrow + g * 4);
        fv4 c = *(const fv4*)(xs + g * 4);
        s += a.x * c.x + a.y * c.y + a.z * c.z + a.w * c.w;
      }
      if (t < 48) vq[e] = s; else vk[e] = s;
    }
  } else if (t < 48) { vq[t] = 0.f; vk[t] = 0.f; }
  __syncthreads();

  if (t < 48) {
    const float tau = *tau_p;
    const float nq2c = G_sh[2352 + t] + 2.f * bqs[t] * vq[t] + (float)NN * bqs[t] * bqs[t];
    const float nq = fmaxf(sqrtf(nq2c), 1e-12f);
    float row[48];
    float mx = -1e30f;
#pragma unroll 1
    for (int qi = 0; qi < 48; ++qi) {
      float nk2c = G_sh[2400 + qi] + 2.f * bks[qi] * vk[qi] + (float)NN * bks[qi] * bks[qi];
      float nk = fmaxf(sqrtf(nk2c), 1e-12f);
      float e = G_sh[t * 49 + qi] + vq[t] * bks[qi] + bqs[t] * vk[qi]
              + (float)NN * bqs[t] * bks[qi];
      float g = e / (nq * nk);
      row[qi] = g; mx = fmaxf(mx, g);
    }
    float s = 0.f;
#pragma unroll 1
    for (int qi = 0; qi < 48; ++qi) { row[qi] = __expf(row[qi] - mx); s += row[qi]; }
    const float inv = 1.f / (s * tau);
    unsigned short* dst = A_out + (((long)b * HH + h) * 48) * 64 + (long)t * 64;
#pragma unroll 1
    for (int qi = 0; qi < 48; ++qi) dst[qi] = f2bf(row[qi] * inv);
#pragma unroll 1
    for (int qi = 48; qi < 64; ++qi) dst[qi] = 0;
  }
}

// ---------------------------------------------------------------------------
// K4: Btf[b][no][h*48+e] = sum_qi A_h[e][qi] * wo[no][h*48+qi]   (MFMA, K=48
// padded to 64). A-operand = wo rows (qi-contiguous), B-operand = A_h rows.
// ---------------------------------------------------------------------------
__global__ __launch_bounds__(256) void build_btf(
    const unsigned short* __restrict__ A_ws, const float* __restrict__ wo,
    unsigned short* __restrict__ btf)
{
  __shared__ unsigned short Wsh[128 * 72];
  __shared__ unsigned short Ash[48 * 72];
  const int nchunk = blockIdx.x, h = blockIdx.y, b = blockIdx.z;
  const int t = threadIdx.x;
  const int wave = t >> 6, lane = t & 63;
  const int no0 = nchunk * 128;

  for (int i = t; i < 128 * 64; i += 256) {
    int r = i >> 6, c = i & 63;
    Wsh[r * 72 + c] = (c < 48) ? f2bf(wo[(long)(no0 + r) * DD + h * 48 + c]) : (unsigned short)0;
  }
  const unsigned short* Asrc = A_ws + ((long)b * HH + h) * 48 * 64;
  for (int i = t; i < 48 * 64; i += 256) {
    int r = i >> 6, c = i & 63;
    Ash[r * 72 + c] = Asrc[r * 64 + c];   // already zero-padded in cols 48..63
  }
  __syncthreads();

  f32x4_t acc[2][3] = {};
#pragma unroll
  for (int ks = 0; ks < 2; ++ks) {
    const int k0 = ks * 32 + ((lane >> 4) << 3);
    bf16x8_t af[2], bfr[3];
#pragma unroll
    for (int mi = 0; mi < 2; ++mi)
      af[mi] = *(const bf16x8_t*)&Wsh[(wave * 32 + mi * 16 + (lane & 15)) * 72 + k0];
#pragma unroll
    for (int nj = 0; nj < 3; ++nj)
      bfr[nj] = *(const bf16x8_t*)&Ash[(nj * 16 + (lane & 15)) * 72 + k0];
#pragma unroll
    for (int mi = 0; mi < 2; ++mi)
#pragma unroll
      for (int nj = 0; nj < 3; ++nj)
        acc[mi][nj] = __builtin_amdgcn_mfma_f32_16x16x32_bf16(af[mi], bfr[nj], acc[mi][nj], 0, 0, 0);
  }

  const int col_l = lane & 15;
  const int rbase = (lane >> 4) << 2;
#pragma unroll
  for (int mi = 0; mi < 2; ++mi)
#pragma unroll
    for (int r = 0; r < 4; ++r) {
      int no = no0 + wave * 32 + mi * 16 + rbase + r;
      unsigned short* dst = btf + ((long)b * DD + no) * DD + h * 48;
#pragma unroll
      for (int nj = 0; nj < 3; ++nj)
        dst[nj * 16 + col_l] = f2bf(acc[mi][nj][r]);
    }
}

// ---------------------------------------------------------------------------
// K5: bias2[b][j] = bo[j] + sum_i bv[i]*Btf[b][j][i]
// ---------------------------------------------------------------------------
__global__ __launch_bounds__(256) void build_bias2(
    const unsigned short* __restrict__ btf, const float* __restrict__ bv,
    const float* __restrict__ bo, float* __restrict__ bias2)
{
  const int bx = blockIdx.x, b = blockIdx.y;
  const int wave = threadIdx.x >> 6, lane = threadIdx.x & 63;
  const int j = bx * 4 + wave;
  const unsigned short* row = btf + ((long)b * DD + j) * DD;
  float s = 0.f;
#pragma unroll
  for (int ii = 0; ii < 12; ++ii) {
    int i = ii * 64 + lane;
    s += bf2f(row[i]) * bv[i];
  }
#pragma unroll
  for (int off = 32; off > 0; off >>= 1) s += __shfl_down(s, off);
  if (lane == 0) bias2[(long)b * DD + j] = bo[j] + s;
}

// ---------------------------------------------------------------------------
extern "C" void kernel_launch(void* const* d_in, const int* in_sizes, int n_in,
                              void* d_out, int out_size, void* d_ws, size_t ws_size,
                              hipStream_t stream)
{
  (void)in_sizes; (void)n_in; (void)out_size;
  const float* x   = (const float*)d_in[0];
  const float* wq  = (const float*)d_in[1];
  const float* bq  = (const float*)d_in[2];
  const float* wk  = (const float*)d_in[3];
  const float* bk  = (const float*)d_in[4];
  const float* wv  = (const float*)d_in[5];
  const float* bv  = (const float*)d_in[6];
  const float* wo  = (const float*)d_in[7];
  const float* bo  = (const float*)d_in[8];
  const float* tau = (const float*)d_in[9];

  char* ws = (char*)d_ws;
  // layout (bytes) — no aliasing needed (306 MB total < proven ws >= 425 MB)
  unsigned short* xb    = (unsigned short*)(ws + 0L);          // 100663296
  unsigned short* xbT   = (unsigned short*)(ws + 100663296L);  // 100663296
  unsigned short* S     = (unsigned short*)(ws + 201326592L);  // 16*768*768*2 = 18874368
  unsigned short* T     = (unsigned short*)(ws + 220200960L);  // 16*1536*768*2 = 37748736
  unsigned short* W2    = (unsigned short*)(ws + 257949696L);  // 2359296
  unsigned short* wvT   = (unsigned short*)(ws + 260308992L);  // 1179648
  float*          zeros = (float*)         (ws + 261488640L);  // 4096
  float*          xsum  = (float*)         (ws + 261492736L);  // 49152
  float*          Gp    = (float*)         (ws + 261541888L);  // 512*2464*4 = 5046272
  unsigned short* A_ws  = (unsigned short*)(ws + 266588160L);  // 1572864
  unsigned short* btf   = (unsigned short*)(ws + 268161024L);  // 18874368
  unsigned short* Ctf   = (unsigned short*)(ws + 287035392L);  // 18874368
  float*          bias2 = (float*)         (ws + 305909760L);  // 49152 -> ends 305958912
  if (ws_size < 305958912ULL) return;

  transpose_cast_x<<<dim3(64, 12, BB), 256, 0, stream>>>(x, xb, xbT);
  small_cast<<<721, 256, 0, stream>>>(wq, wk, wv, W2, wvT, zeros);
  colsum<<<dim3(192, BB), 256, 0, stream>>>(xbT, xsum);

  // S[b] = x[b]^T x[b]  (768x768 symmetric, K=4096): 21 triangle tiles/batch
  gemm_bt<1, 1><<<16 * 21, 256, 0, stream>>>(
      xbT, NN, (long)DD * NN, xbT, NN, (long)DD * NN,
      S, DD, (long)DD * DD, zeros, 0L, NN, 21, 6);

  // T[b] = W2 * S[b]  (1536x768, K=768; S symmetric -> Bt=S), bf16 out
  gemm_bt<1, 0><<<16 * 72, 256, 0, stream>>>(
      W2, DD, 0L, S, DD, (long)DD * DD,
      T, DD, (long)1536 * DD, zeros, 0L, DD, 72, 6);

  energy_partial2<<<dim3(2, HH, BB), 256, 0, stream>>>(T, W2, Gp);
  energy_finish2<<<dim3(HH, BB), 256, 0, stream>>>(Gp, xsum, wq, wk, bq, bk, tau, A_ws);

  build_btf<<<dim3(6, HH, BB), 256, 0, stream>>>(A_ws, wo, btf);
  build_bias2<<<dim3(192, BB), 256, 0, stream>>>(btf, bv, bo, bias2);

  // Ctf[b] = Btf[b] * wv  (768x768, K=768), bf16 out
  gemm_bt<1, 0><<<16 * 36, 256, 0, stream>>>(
      btf, DD, (long)DD * DD, wvT, DD, 0L,
      Ctf, DD, (long)DD * DD, zeros, 0L, DD, 36, 6);

  // out[b] = x[b] * Ctf[b]^T + bias2[b]  (4096x768, K=768), f32 out
  gemm_bt<0, 0><<<16 * 192, 256, 0, stream>>>(
      xb, DD, (long)NN * DD, Ctf, DD, (long)DD * DD,
      d_out, DD, (long)NN * DD, bias2, (long)DD, DD, 192, 6);
}

// Round 8
// 472.064 us; speedup vs baseline: 2.5723x; 1.0257x over previous
//
#include <hip/hip_runtime.h>
#include <hip/hip_bf16.h>

typedef __attribute__((ext_vector_type(8))) short bf16x8_t;   // MFMA A/B frag (8 bf16)
typedef __attribute__((ext_vector_type(4))) float f32x4_t;    // MFMA C/D frag
typedef __attribute__((ext_vector_type(4))) float fv4;
typedef __attribute__((ext_vector_type(4))) unsigned short us4_t;
typedef __attribute__((ext_vector_type(8))) unsigned short us8_t;

// Problem constants
static constexpr int BB = 16, NN = 4096, DD = 768, HH = 16, EE = 48;

__device__ __forceinline__ unsigned short f2bf(float f) {
  unsigned int u = __float_as_uint(f);
  u += 0x7fffu + ((u >> 16) & 1u);   // RNE; inputs are finite
  return (unsigned short)(u >> 16);
}
__device__ __forceinline__ float bf2f(unsigned short s) {
  unsigned int u = ((unsigned int)s) << 16;
  return __uint_as_float(u);
}

__device__ __forceinline__ void load_lds16(const void* g, void* l) {
  __builtin_amdgcn_global_load_lds((const __attribute__((address_space(1))) void*)g,
                                   (__attribute__((address_space(3))) void*)l, 16, 0, 0);
}

// ---------------------------------------------------------------------------
// 64x64 f32->bf16 transposing tile cast via LDS. dst[c][r] = src[r][c].
// Optional pass-through row-major bf16 write (thru).
// ---------------------------------------------------------------------------
template<int WRITE_THRU>
__device__ __forceinline__ void tcast64(const float* __restrict__ src, int sld,
                                        unsigned short* __restrict__ dst, int dld,
                                        unsigned short* __restrict__ thru, int tld, int t)
{
  __shared__ float L[64][65];
#pragma unroll
  for (int q = 0; q < 4; ++q) {
    const int fi = t + q * 256;          // 0..1023
    const int r = fi >> 4, c4 = fi & 15; // row, col-group of 4
    fv4 v = *(const fv4*)(src + (long)r * sld + c4 * 4);
    L[r][c4 * 4 + 0] = v.x; L[r][c4 * 4 + 1] = v.y;
    L[r][c4 * 4 + 2] = v.z; L[r][c4 * 4 + 3] = v.w;
    if (WRITE_THRU) {
      us4_t o; o.x = f2bf(v.x); o.y = f2bf(v.y); o.z = f2bf(v.z); o.w = f2bf(v.w);
      *(us4_t*)(thru + (long)r * tld + c4 * 4) = o;
    }
  }
  __syncthreads();
#pragma unroll
  for (int q = 0; q < 2; ++q) {
    const int wi = t + q * 256;          // 0..511
    const int rr = wi >> 3, ng = wi & 7; // dst row, 8-col group
    us8_t o;
#pragma unroll
    for (int j = 0; j < 8; ++j) o[j] = f2bf(L[ng * 8 + j][rr]);
    *(us8_t*)(dst + (long)rr * dld + ng * 8) = o;
  }
  __syncthreads();
}

// K1a: x -> xb (row-major bf16) AND xbT (transposed bf16 [b][d][n])
__global__ __launch_bounds__(256) void transpose_cast_x(
    const float* __restrict__ x, unsigned short* __restrict__ xb,
    unsigned short* __restrict__ xbT)
{
  const int nx = blockIdx.x, dx = blockIdx.y, b = blockIdx.z;
  const int n0 = nx * 64, d0 = dx * 64;
  const float* src = x + ((long)b * NN + n0) * DD + d0;
  unsigned short* thru = xb + ((long)b * NN + n0) * DD + d0;
  unsigned short* dst = xbT + ((long)b * DD + d0) * NN + n0;
  tcast64<1>(src, DD, dst, NN, thru, DD, threadIdx.x);
}

// K1b: W2=[wq;wk] bf16 [1536][768]; wvT bf16 [768(k)][768(i)] = wv^T; zeros
__global__ __launch_bounds__(256) void small_cast(
    const float* __restrict__ wq, const float* __restrict__ wk, const float* __restrict__ wv,
    unsigned short* __restrict__ W2, unsigned short* __restrict__ wvT,
    float* __restrict__ zeros)
{
  const int blk = blockIdx.x, t = threadIdx.x;
  if (blk < 576) {
    // 1536x768 = 1179648 elems = 576 blocks * 512 fv4-ish groups
#pragma unroll
    for (int q = 0; q < 2; ++q) {
      long g = (long)blk * 512 + t * 2 + q;   // fv4 index
      long e0 = g * 4;
      int row = (int)(e0 / DD), col = (int)(e0 % DD);
      const float* src = (row < DD) ? (wq + (long)row * DD + col)
                                    : (wk + (long)(row - DD) * DD + col);
      fv4 v = *(const fv4*)src;
      us4_t o; o.x = f2bf(v.x); o.y = f2bf(v.y); o.z = f2bf(v.z); o.w = f2bf(v.w);
      *(us4_t*)(W2 + e0) = o;
    }
  } else if (blk < 720) {
    const int tile = blk - 576;
    const int ti = tile / 12, tj = tile % 12;  // k-block, i-block
    const int k0 = ti * 64, i0 = tj * 64;
    // wvT[k][i] = wv[i][k]
    tcast64<0>(wv + (long)i0 * DD + k0, DD, wvT + (long)k0 * DD + i0, DD, nullptr, 0, t);
  } else {
#pragma unroll
    for (int q = 0; q < 4; ++q) zeros[t * 4 + q] = 0.f;
  }
}

// K1c: xsum[b][d] = sum_n x[b][n][d], read from xbT rows (contiguous).
__global__ __launch_bounds__(256) void colsum(
    const unsigned short* __restrict__ xbT, float* __restrict__ xsum)
{
  const int bx = blockIdx.x, b = blockIdx.y;
  const int wave = threadIdx.x >> 6, lane = threadIdx.x & 63;
  const int d = bx * 4 + wave;
  const unsigned short* row = xbT + ((long)b * DD + d) * NN;
  float s = 0.f;
#pragma unroll
  for (int it = 0; it < 8; ++it) {
    us8_t v = *(const us8_t*)(row + (it * 64 + lane) * 8);
#pragma unroll
    for (int j = 0; j < 8; ++j) s += bf2f(v[j]);
  }
#pragma unroll
  for (int off = 32; off > 0; off >>= 1) s += __shfl_down(s, off);
  if (lane == 0) xsum[(long)b * DD + d] = s;
}

// ---------------------------------------------------------------------------
// bf16 GEMM, C[m][n] = sum_k A[m][k] * Bt[n][k] + bias[n]  (per-z bias optional)
// 128x128 tile, BK=64, 4 waves (2x2 of 64x64), XOR-swizzled LDS (round-7:
// bank conflicts 9.4M -> 0, verified).
// Round-8 upgrade: 2-phase double-buffer (T3-minimum). Round-7 counters
// showed MfmaUtil 23% / HBM 25% — latency-bound: the barrier right after
// stage-issue drains vmcnt(0) with zero work to hide it. Now STAGE(next)
// is issued BEFORE the ds_read+MFMA phase on cur, and the single
// end-of-tile __syncthreads' vmcnt(0) drain lands after ~the whole MFMA
// phase has covered the load latency. One barrier per K-tile (was 2).
// LDS 64KB -> 2 blocks/CU (ILP replaces TLP). setprio skipped: T5 is
// null at 2-phase (regime gate, m230).
// 1-D grid + XCD-chunked bijective swizzle (T1; all call sites nwg%8==0).
// SYM=1 (A==Bt, square): upper-triangle tiles only; mirror tile written
// transposed via packed us4. OUT_BF16=1 -> bf16 store, else f32 store.
// ---------------------------------------------------------------------------
template<int OUT_BF16, int SYM>
__global__ __launch_bounds__(256) void gemm_bt(
    const unsigned short* __restrict__ A, int lda, long aStride,
    const unsigned short* __restrict__ Bt, int ldb, long bStride,
    void* __restrict__ Cv, int ldc, long cStride,
    const float* __restrict__ bias, long biasStride, int K,
    int perB, int nt)
{
  __shared__ unsigned short As[2][128 * 64];
  __shared__ unsigned short Bs[2][128 * 64];
  const int nwg = gridDim.x;
  const int bid = blockIdx.x;
  const int wid = (bid & 7) * (nwg >> 3) + (bid >> 3);   // XCD-chunked
  const int zb = wid / perB;
  const int t0 = wid % perB;
  int i0, j0;
  if (SYM) {
    int tt = t0; i0 = 0;
    while (tt >= nt - i0) { tt -= nt - i0; ++i0; }
    j0 = i0 + tt;
  } else {
    i0 = t0 / nt; j0 = t0 % nt;   // n fastest: consecutive blocks share A-panel
  }
  const unsigned short* Ab = A + (long)zb * aStride;
  const unsigned short* Bb = Bt + (long)zb * bStride;
  const float* bz = bias + (long)zb * biasStride;
  const long m0 = (long)i0 * 128;
  const int n0 = j0 * 128;
  const int t = threadIdx.x;
  const int wave = t >> 6, lane = t & 63;
  const int wr = wave >> 1, wc = wave & 1;

  f32x4_t acc[4][4] = {};

  // staging: thread t covers LDS bytes p*4096 + t*16 (p=0..3, linear dest).
  // row = p*32 + (t>>3); block c = t&7; source block = c ^ (row&7).
  const int srow = t >> 3;                                // 0..31
  const long scol = (long)(((t & 7) ^ (srow & 7)) << 3);  // elems

  auto STAGE = [&](int bsel, int kt) {
#pragma unroll
    for (int p = 0; p < 4; ++p) {
      load_lds16(Ab + (m0 + p * 32 + srow) * (long)lda + kt + scol,
                 &As[bsel][wave * 512 + p * 2048]);
      load_lds16(Bb + (long)(n0 + p * 32 + srow) * ldb + kt + scol,
                 &Bs[bsel][wave * 512 + p * 2048]);
    }
  };

  STAGE(0, 0);
  __syncthreads();

  int cur = 0;
  for (int kt = 0; kt < K; kt += 64) {
    if (kt + 64 < K) STAGE(cur ^ 1, kt + 64);   // prefetch next tile (async)
#pragma unroll
    for (int kk = 0; kk < 2; ++kk) {
      // frag read (swizzled): row = W*64+f*16+(lane&15); logical blk = kk*4+(lane>>4)
      const int cswz = (((kk << 2) + (lane >> 4)) ^ (lane & 7)) << 4;   // bytes
      bf16x8_t af[4], bfr[4];
#pragma unroll
      for (int f = 0; f < 4; ++f) {
        af[f]  = *(const bf16x8_t*)((const char*)&As[cur][0] + (wr * 64 + f * 16 + (lane & 15)) * 128 + cswz);
        bfr[f] = *(const bf16x8_t*)((const char*)&Bs[cur][0] + (wc * 64 + f * 16 + (lane & 15)) * 128 + cswz);
      }
#pragma unroll
      for (int i = 0; i < 4; ++i)
#pragma unroll
        for (int j = 0; j < 4; ++j)
          acc[i][j] = __builtin_amdgcn_mfma_f32_16x16x32_bf16(af[i], bfr[j], acc[i][j], 0, 0, 0);
    }
    __syncthreads();   // drains vmcnt(0): prefetch had the whole MFMA phase
    cur ^= 1;
  }

  // epilogue: D col = lane&15, row = (lane>>4)*4 + r  (m89-verified layout)
  const int col_l = lane & 15;
  const int rbase = (lane >> 4) << 2;
#pragma unroll
  for (int i = 0; i < 4; ++i) {
    const long growb = m0 + wr * 64 + i * 16 + rbase;
#pragma unroll
    for (int j = 0; j < 4; ++j) {
      const int col = n0 + wc * 64 + j * 16 + col_l;
      if (OUT_BF16) {
        const float bcol = bz[col];
        us4_t o;
#pragma unroll
        for (int r = 0; r < 4; ++r) o[r] = f2bf(acc[i][j][r] + bcol);
        unsigned short* cb = (unsigned short*)Cv + (long)zb * cStride;
#pragma unroll
        for (int r = 0; r < 4; ++r) cb[(growb + r) * ldc + col] = o[r];
        if (SYM && i0 != j0)   // mirror tile, transposed, packed 8B store
          *(us4_t*)(cb + (long)col * ldc + growb) = o;
      } else {
#pragma unroll
        for (int r = 0; r < 4; ++r) {
          float* crow = (float*)Cv + (long)zb * cStride + (growb + r) * ldc;
          crow[col] = acc[i][j][r] + bz[col];
        }
      }
    }
  }
}

// ---------------------------------------------------------------------------
// K3a: per (b,h,kc): partial E_h = Tq_h * wk_h^T over k' in [kc*384,+384),
// plus diag(Tq_h*wq_h^T) -> nq2, diag(Tk_h*wk_h^T) -> nk2 (MFMA diag trick).
// Tq_h = T[b] rows [h*48,+48), Tk_h = rows [768+h*48,+48); same for W2.
// Staged via global_load_lds with the round-4-proven 16B-block XOR swizzle
// (pre-swizzled global source + swizzled frag reads; rows 256B).
// Writes fp32 partials Gp[((b*H+h)*2+kc)][2464]:
//   [0..2352) = E (48 rows x stride 49), [2352..2400) nq2, [2400..2448) nk2.
// ---------------------------------------------------------------------------
#define GP_STRIDE 2464

__global__ __launch_bounds__(256) void energy_partial2(
    const unsigned short* __restrict__ T, const unsigned short* __restrict__ W2,
    float* __restrict__ Gp)
{
  __shared__ unsigned short Ts[2][48 * 128];   // Tq, Tk tiles (12KB each)
  __shared__ unsigned short Ws[2][48 * 128];   // wq, wk tiles
  __shared__ float G_sh[2448];

  const int kc = blockIdx.x, h = blockIdx.y, b = blockIdx.z;
  const int t = threadIdx.x;
  const int wave = t >> 6, lane = t & 63;

  for (int i = t; i < 2448; i += 256) G_sh[i] = 0.f;

  f32x4_t accG[3][3] = {};
  f32x4_t accQ[3] = {};
  f32x4_t accK[3] = {};

  // staging source offsets: linear LDS byte L = p*4096 + wave*1024 + lane*16
  // -> e = L>>8, 16B-block blk = (L>>4)&15; inverse-swizzled source k-block
  long qoff[3];
#pragma unroll
  for (int p = 0; p < 3; ++p) {
    const int L = p * 4096 + wave * 1024 + lane * 16;
    const int e = L >> 8;
    const int blk = (L >> 4) & 15;
    const int sblk = blk ^ (e & 7);
    qoff[p] = (long)e * DD + sblk * 8;
  }
  const unsigned short* Tq = T + ((long)b * 1536 + h * 48) * DD;
  const unsigned short* Tk = Tq + (long)DD * DD;
  const unsigned short* Wq = W2 + (long)h * 48 * DD;
  const unsigned short* Wk = Wq + (long)DD * DD;

  // frag read offsets (bytes, swizzled): e = f*16+(lane&15), k-blk = wave*4+(lane>>4)
  int foff[3];
#pragma unroll
  for (int f = 0; f < 3; ++f) {
    const int e = f * 16 + (lane & 15);
    foff[f] = e * 256 + (((wave * 4 + (lane >> 4)) ^ (e & 7)) << 4);
  }
  __syncthreads();

  for (int ci = 0; ci < 3; ++ci) {
    const int col0 = kc * 384 + ci * 128;
#pragma unroll
    for (int p = 0; p < 3; ++p) {
      load_lds16(Tq + qoff[p] + col0, &Ts[0][p * 2048] + wave * 512);
      load_lds16(Tk + qoff[p] + col0, &Ts[1][p * 2048] + wave * 512);
      load_lds16(Wq + qoff[p] + col0, &Ws[0][p * 2048] + wave * 512);
      load_lds16(Wk + qoff[p] + col0, &Ws[1][p * 2048] + wave * 512);
    }
    __syncthreads();
    bf16x8_t tq[3], tk[3], wqf[3], wkf[3];
#pragma unroll
    for (int f = 0; f < 3; ++f) {
      tq[f]  = *(const bf16x8_t*)((const char*)&Ts[0][0] + foff[f]);
      tk[f]  = *(const bf16x8_t*)((const char*)&Ts[1][0] + foff[f]);
      wqf[f] = *(const bf16x8_t*)((const char*)&Ws[0][0] + foff[f]);
      wkf[f] = *(const bf16x8_t*)((const char*)&Ws[1][0] + foff[f]);
    }
#pragma unroll
    for (int i = 0; i < 3; ++i) {
      accQ[i] = __builtin_amdgcn_mfma_f32_16x16x32_bf16(tq[i], wqf[i], accQ[i], 0, 0, 0);
      accK[i] = __builtin_amdgcn_mfma_f32_16x16x32_bf16(tk[i], wkf[i], accK[i], 0, 0, 0);
#pragma unroll
      for (int j = 0; j < 3; ++j)
        accG[i][j] = __builtin_amdgcn_mfma_f32_16x16x32_bf16(tq[i], wkf[j], accG[i][j], 0, 0, 0);
    }
    __syncthreads();
  }

  // cross-wave reduce into LDS
#pragma unroll
  for (int i = 0; i < 3; ++i)
#pragma unroll
    for (int j = 0; j < 3; ++j) {
      int e = i * 16 + ((lane >> 4) << 2);
      int qi = j * 16 + (lane & 15);
#pragma unroll
      for (int r = 0; r < 4; ++r) atomicAdd(&G_sh[(e + r) * 49 + qi], accG[i][j][r]);
    }
  // diagonal lanes contribute the norms
  if ((lane >> 4) == ((lane & 15) >> 2)) {
    int r = (lane & 15) & 3;
#pragma unroll
    for (int f = 0; f < 3; ++f) {
      atomicAdd(&G_sh[2352 + f * 16 + (lane & 15)], accQ[f][r]);
      atomicAdd(&G_sh[2400 + f * 16 + (lane & 15)], accK[f][r]);
    }
  }
  __syncthreads();

  float* out = Gp + (long)(((b * HH + h) << 1) + kc) * GP_STRIDE;
  for (int i = t; i < 2448; i += 256) out[i] = G_sh[i];
}

// ---------------------------------------------------------------------------
// K3b: per (b,h): reduce 2 partials, apply bias corrections (exact-zero-cost
// when bq=bk=0: runtime check skips them), norms, softmax, /tau.
// Writes A bf16 padded [48][64] (cols 48..63 zero) for build_btf.
// ---------------------------------------------------------------------------
__global__ __launch_bounds__(256) void energy_finish2(
    const float* __restrict__ Gp, const float* __restrict__ xsum,
    const float* __restrict__ wq, const float* __restrict__ wk,
    const float* __restrict__ bq, const float* __restrict__ bk,
    const float* __restrict__ tau_p, unsigned short* __restrict__ A_out)
{
  __shared__ float G_sh[2448];
  __shared__ float vq[48], vk[48], bqs[48], bks[48];
  __shared__ int has_bias;
  const int h = blockIdx.x, b = blockIdx.y;
  const int t = threadIdx.x;

  const float* base = Gp + (long)((b * HH + h) << 1) * GP_STRIDE;
  for (int i = t; i < 2448; i += 256)
    G_sh[i] = base[i] + base[GP_STRIDE + i];
  if (t < 48) { bqs[t] = bq[h * 48 + t]; bks[t] = bk[h * 48 + t]; }
  __syncthreads();
  if (t == 0) {
    float s = 0.f;
    for (int i = 0; i < 48; ++i) s += fabsf(bqs[i]) + fabsf(bks[i]);
    has_bias = (s != 0.f);
  }
  __syncthreads();
  if (has_bias) {
    // vq[e] = wq_h[e,:] . xsum[b],  vk[q] = wk_h[q,:] . xsum[b]
    if (t < 96) {
      const int e = t < 48 ? t : t - 48;
      const float* wrow = (t < 48 ? wq : wk) + (long)(h * 48 + e) * DD;
      const float* xs = xsum + (long)b * DD;
      float s = 0.f;
      for (int g = 0; g < DD / 4; ++g) {
        fv4 a = *(const fv4*)(wrow + g * 4);
        fv4 c = *(const fv4*)(xs + g * 4);
        s += a.x * c.x + a.y * c.y + a.z * c.z + a.w * c.w;
      }
      if (t < 48) vq[e] = s; else vk[e] = s;
    }
  } else if (t < 48) { vq[t] = 0.f; vk[t] = 0.f; }
  __syncthreads();

  if (t < 48) {
    const float tau = *tau_p;
    const float nq2c = G_sh[2352 + t] + 2.f * bqs[t] * vq[t] + (float)NN * bqs[t] * bqs[t];
    const float nq = fmaxf(sqrtf(nq2c), 1e-12f);
    float row[48];
    float mx = -1e30f;
#pragma unroll 1
    for (int qi = 0; qi < 48; ++qi) {
      float nk2c = G_sh[2400 + qi] + 2.f * bks[qi] * vk[qi] + (float)NN * bks[qi] * bks[qi];
      float nk = fmaxf(sqrtf(nk2c), 1e-12f);
      float e = G_sh[t * 49 + qi] + vq[t] * bks[qi] + bqs[t] * vk[qi]
              + (float)NN * bqs[t] * bks[qi];
      float g = e / (nq * nk);
      row[qi] = g; mx = fmaxf(mx, g);
    }
    float s = 0.f;
#pragma unroll 1
    for (int qi = 0; qi < 48; ++qi) { row[qi] = __expf(row[qi] - mx); s += row[qi]; }
    const float inv = 1.f / (s * tau);
    unsigned short* dst = A_out + (((long)b * HH + h) * 48) * 64 + (long)t * 64;
#pragma unroll 1
    for (int qi = 0; qi < 48; ++qi) dst[qi] = f2bf(row[qi] * inv);
#pragma unroll 1
    for (int qi = 48; qi < 64; ++qi) dst[qi] = 0;
  }
}

// ---------------------------------------------------------------------------
// K4: Btf[b][no][h*48+e] = sum_qi A_h[e][qi] * wo[no][h*48+qi]   (MFMA, K=48
// padded to 64). A-operand = wo rows (qi-contiguous), B-operand = A_h rows.
// ---------------------------------------------------------------------------
__global__ __launch_bounds__(256) void build_btf(
    const unsigned short* __restrict__ A_ws, const float* __restrict__ wo,
    unsigned short* __restrict__ btf)
{
  __shared__ unsigned short Wsh[128 * 72];
  __shared__ unsigned short Ash[48 * 72];
  const int nchunk = blockIdx.x, h = blockIdx.y, b = blockIdx.z;
  const int t = threadIdx.x;
  const int wave = t >> 6, lane = t & 63;
  const int no0 = nchunk * 128;

  for (int i = t; i < 128 * 64; i += 256) {
    int r = i >> 6, c = i & 63;
    Wsh[r * 72 + c] = (c < 48) ? f2bf(wo[(long)(no0 + r) * DD + h * 48 + c]) : (unsigned short)0;
  }
  const unsigned short* Asrc = A_ws + ((long)b * HH + h) * 48 * 64;
  for (int i = t; i < 48 * 64; i += 256) {
    int r = i >> 6, c = i & 63;
    Ash[r * 72 + c] = Asrc[r * 64 + c];   // already zero-padded in cols 48..63
  }
  __syncthreads();

  f32x4_t acc[2][3] = {};
#pragma unroll
  for (int ks = 0; ks < 2; ++ks) {
    const int k0 = ks * 32 + ((lane >> 4) << 3);
    bf16x8_t af[2], bfr[3];
#pragma unroll
    for (int mi = 0; mi < 2; ++mi)
      af[mi] = *(const bf16x8_t*)&Wsh[(wave * 32 + mi * 16 + (lane & 15)) * 72 + k0];
#pragma unroll
    for (int nj = 0; nj < 3; ++nj)
      bfr[nj] = *(const bf16x8_t*)&Ash[(nj * 16 + (lane & 15)) * 72 + k0];
#pragma unroll
    for (int mi = 0; mi < 2; ++mi)
#pragma unroll
      for (int nj = 0; nj < 3; ++nj)
        acc[mi][nj] = __builtin_amdgcn_mfma_f32_16x16x32_bf16(af[mi], bfr[nj], acc[mi][nj], 0, 0, 0);
  }

  const int col_l = lane & 15;
  const int rbase = (lane >> 4) << 2;
#pragma unroll
  for (int mi = 0; mi < 2; ++mi)
#pragma unroll
    for (int r = 0; r < 4; ++r) {
      int no = no0 + wave * 32 + mi * 16 + rbase + r;
      unsigned short* dst = btf + ((long)b * DD + no) * DD + h * 48;
#pragma unroll
      for (int nj = 0; nj < 3; ++nj)
        dst[nj * 16 + col_l] = f2bf(acc[mi][nj][r]);
    }
}

// ---------------------------------------------------------------------------
// K5: bias2[b][j] = bo[j] + sum_i bv[i]*Btf[b][j][i]
// ---------------------------------------------------------------------------
__global__ __launch_bounds__(256) void build_bias2(
    const unsigned short* __restrict__ btf, const float* __restrict__ bv,
    const float* __restrict__ bo, float* __restrict__ bias2)
{
  const int bx = blockIdx.x, b = blockIdx.y;
  const int wave = threadIdx.x >> 6, lane = threadIdx.x & 63;
  const int j = bx * 4 + wave;
  const unsigned short* row = btf + ((long)b * DD + j) * DD;
  float s = 0.f;
#pragma unroll
  for (int ii = 0; ii < 12; ++ii) {
    int i = ii * 64 + lane;
    s += bf2f(row[i]) * bv[i];
  }
#pragma unroll
  for (int off = 32; off > 0; off >>= 1) s += __shfl_down(s, off);
  if (lane == 0) bias2[(long)b * DD + j] = bo[j] + s;
}

// ---------------------------------------------------------------------------
extern "C" void kernel_launch(void* const* d_in, const int* in_sizes, int n_in,
                              void* d_out, int out_size, void* d_ws, size_t ws_size,
                              hipStream_t stream)
{
  (void)in_sizes; (void)n_in; (void)out_size;
  const float* x   = (const float*)d_in[0];
  const float* wq  = (const float*)d_in[1];
  const float* bq  = (const float*)d_in[2];
  const float* wk  = (const float*)d_in[3];
  const float* bk  = (const float*)d_in[4];
  const float* wv  = (const float*)d_in[5];
  const float* bv  = (const float*)d_in[6];
  const float* wo  = (const float*)d_in[7];
  const float* bo  = (const float*)d_in[8];
  const float* tau = (const float*)d_in[9];

  char* ws = (char*)d_ws;
  // layout (bytes) — no aliasing needed (306 MB total < proven ws >= 425 MB)
  unsigned short* xb    = (unsigned short*)(ws + 0L);          // 100663296
  unsigned short* xbT   = (unsigned short*)(ws + 100663296L);  // 100663296
  unsigned short* S     = (unsigned short*)(ws + 201326592L);  // 16*768*768*2 = 18874368
  unsigned short* T     = (unsigned short*)(ws + 220200960L);  // 16*1536*768*2 = 37748736
  unsigned short* W2    = (unsigned short*)(ws + 257949696L);  // 2359296
  unsigned short* wvT   = (unsigned short*)(ws + 260308992L);  // 1179648
  float*          zeros = (float*)         (ws + 261488640L);  // 4096
  float*          xsum  = (float*)         (ws + 261492736L);  // 49152
  float*          Gp    = (float*)         (ws + 261541888L);  // 512*2464*4 = 5046272
  unsigned short* A_ws  = (unsigned short*)(ws + 266588160L);  // 1572864
  unsigned short* btf   = (unsigned short*)(ws + 268161024L);  // 18874368
  unsigned short* Ctf   = (unsigned short*)(ws + 287035392L);  // 18874368
  float*          bias2 = (float*)         (ws + 305909760L);  // 49152 -> ends 305958912
  if (ws_size < 305958912ULL) return;

  transpose_cast_x<<<dim3(64, 12, BB), 256, 0, stream>>>(x, xb, xbT);
  small_cast<<<721, 256, 0, stream>>>(wq, wk, wv, W2, wvT, zeros);
  colsum<<<dim3(192, BB), 256, 0, stream>>>(xbT, xsum);

  // S[b] = x[b]^T x[b]  (768x768 symmetric, K=4096): 21 triangle tiles/batch
  gemm_bt<1, 1><<<16 * 21, 256, 0, stream>>>(
      xbT, NN, (long)DD * NN, xbT, NN, (long)DD * NN,
      S, DD, (long)DD * DD, zeros, 0L, NN, 21, 6);

  // T[b] = W2 * S[b]  (1536x768, K=768; S symmetric -> Bt=S), bf16 out
  gemm_bt<1, 0><<<16 * 72, 256, 0, stream>>>(
      W2, DD, 0L, S, DD, (long)DD * DD,
      T, DD, (long)1536 * DD, zeros, 0L, DD, 72, 6);

  energy_partial2<<<dim3(2, HH, BB), 256, 0, stream>>>(T, W2, Gp);
  energy_finish2<<<dim3(HH, BB), 256, 0, stream>>>(Gp, xsum, wq, wk, bq, bk, tau, A_ws);

  build_btf<<<dim3(6, HH, BB), 256, 0, stream>>>(A_ws, wo, btf);
  build_bias2<<<dim3(192, BB), 256, 0, stream>>>(btf, bv, bo, bias2);

  // Ctf[b] = Btf[b] * wv  (768x768, K=768), bf16 out
  gemm_bt<1, 0><<<16 * 36, 256, 0, stream>>>(
      btf, DD, (long)DD * DD, wvT, DD, 0L,
      Ctf, DD, (long)DD * DD, zeros, 0L, DD, 36, 6);

  // out[b] = x[b] * Ctf[b]^T + bias2[b]  (4096x768, K=768), f32 out
  gemm_bt<0, 0><<<16 * 192, 256, 0, stream>>>(
      xb, DD, (long)NN * DD, Ctf, DD, (long)DD * DD,
      d_out, DD, (long)NN * DD, bias2, (long)DD, DD, 192, 6);
}